// Round 10
// baseline (979.783 us; speedup 1.0000x reference)
//
#include <hip/hip_runtime.h>
#include <math.h>

// GCNNet: N=8192, D=512. Same pipeline as round 9; chain consolidated:
//   - reduce<2>+softmax+transpose fused (reduce_softmax16_t)
//   - colsum fused into splitK reduce (reduce1_colsum); scale_vec folded away.
// GEMM engine: 256x256-tile 8-wave 8-phase schedule (K-half regions, counted
// vmcnt, raw s_barrier, 128KB dynamic LDS); round-8 engine as fallback.

typedef __attribute__((ext_vector_type(8))) short bf16x8;     // raw 16B container
typedef __attribute__((ext_vector_type(8))) _Float16 f16x8;
typedef __attribute__((ext_vector_type(4))) float f32x4;
typedef __attribute__((ext_vector_type(4))) unsigned short us4;

__device__ __forceinline__ unsigned short f2h(float x) {
    _Float16 h = (_Float16)x;
    return __builtin_bit_cast(unsigned short, h);
}
__device__ __forceinline__ float h2f(unsigned short u) {
    return (float)__builtin_bit_cast(_Float16, u);
}

__device__ __forceinline__ void gload_lds16(const char* g, char* l) {
    __builtin_amdgcn_global_load_lds(
        (const __attribute__((address_space(1))) unsigned int*)g,
        (__attribute__((address_space(3))) unsigned int*)l, 16, 0, 0);
}

// XOR bank swizzles (involutions, preserve 16B alignment)
__device__ __forceinline__ int swz(int o) {
    return o ^ (((o >> 7) & 7) << 4);
}
__device__ __forceinline__ int swzk(int o) {
    return o ^ (((o >> 7) & 3) << 4);
}

__device__ __forceinline__ f32x4 mfma16(bf16x8 a, bf16x8 b, f32x4 c) {
    return __builtin_amdgcn_mfma_f32_16x16x32_f16(
        __builtin_bit_cast(f16x8, a), __builtin_bit_cast(f16x8, b), c, 0, 0, 0);
}

// ================================================================ 8-phase GEMM
// A [M,K] fp16 row-major, B [Ncol,K] fp16 row-major. 256x256 tile, 8 waves.
// BK=64 as two K-halves; regions A_k0,A_k1,B_k0,B_k1 (16KB each); dbuf 128KB.
// splitK via gridDim.z. EPI: 0 f32 (+zoff), 2 sigmoid f32, 3 fp16.
template<int EPI>
__global__ __launch_bounds__(512, 1)
void gemm8p(const unsigned short* __restrict__ A, const unsigned short* __restrict__ B,
            float* __restrict__ Cf, unsigned short* __restrict__ Ch,
            int M, int Ncol, int Kdim)
{
    extern __shared__ char lds[];            // 131072 bytes
    constexpr int RSZ = 16384;               // region bytes

    const int tid = threadIdx.x;
    const int w = tid >> 6, lane = tid & 63;
    const int wr = w >> 2, wc = w & 3;       // 2 x 4 wave grid
    const int l15 = lane & 15, kq = lane >> 4;

    const int gx = gridDim.x;
    const int nwg = gx * gridDim.y;
    const int lid = blockIdx.y * gx + blockIdx.x;
    const int tl = (lid & 7) * (nwg >> 3) + (lid >> 3);
    const int m0 = (tl / gx) * 256, n0 = (tl % gx) * 256;

    const int kseg = Kdim / gridDim.z;
    const int kbeg = blockIdx.z * kseg;
    const int T = kseg >> 6;                 // BK = 64
    const size_t zoff = (size_t)blockIdx.z * ((size_t)M * Ncol);

    const int Kb = Kdim * 2;
    const char* gp[4][2];
    {
        const char* Ab = (const char*)A + (size_t)m0 * Kb + (size_t)kbeg * 2;
        const char* Bb = (const char*)B + (size_t)n0 * Kb + (size_t)kbeg * 2;
#pragma unroll
        for (int r = 0; r < 4; ++r) {
            const char* base = (r < 2) ? Ab : Bb;
            const int khalf = r & 1;
#pragma unroll
            for (int j = 0; j < 2; ++j) {
                const int moff = swzk((w * 2 + j) * 1024 + lane * 16);
                gp[r][j] = base + (size_t)(moff >> 6) * Kb + khalf * 64 + (moff & 63);
            }
        }
    }

    auto stage = [&](int r, int tile) {
        char* dst = lds + (tile & 1) * 65536 + r * RSZ + w * 2048;
        gload_lds16(gp[r][0] + (size_t)tile * 128, dst);
        gload_lds16(gp[r][1] + (size_t)tile * 128, dst + 1024);
    };

    int aoff[8], boff[4];
#pragma unroll
    for (int mf = 0; mf < 8; ++mf)
        aoff[mf] = swzk((wr * 128 + mf * 16 + l15) * 64 + kq * 16);
#pragma unroll
    for (int n = 0; n < 4; ++n)
        boff[n] = swzk((wc * 64 + n * 16 + l15) * 64 + kq * 16);

    f32x4 acc[8][4];
#pragma unroll
    for (int m = 0; m < 8; ++m)
#pragma unroll
        for (int n = 0; n < 4; ++n)
            acc[m][n] = (f32x4)(0.f);

    stage(2, 0); stage(0, 0); stage(3, 0); stage(1, 0);
    stage(2, 1); stage(0, 1); stage(3, 1);
    asm volatile("s_waitcnt vmcnt(10)" ::: "memory");
    __builtin_amdgcn_s_barrier();

    for (int t = 0; t < T; ++t) {
        const char* Lb = lds + (t & 1) * 65536;
        bf16x8 bfr[4], afr[4];

        // phase 0: kk0, mf 0-3
#pragma unroll
        for (int n = 0; n < 4; ++n) bfr[n] = *(const bf16x8*)(Lb + 2 * RSZ + boff[n]);
#pragma unroll
        for (int m = 0; m < 4; ++m) afr[m] = *(const bf16x8*)(Lb + 0 * RSZ + aoff[m]);
        if (t + 1 < T) stage(1, t + 1);
        __builtin_amdgcn_s_barrier();
        __builtin_amdgcn_s_setprio(1);
#pragma unroll
        for (int n = 0; n < 4; ++n)
#pragma unroll
            for (int m = 0; m < 4; ++m)
                acc[m][n] = mfma16(afr[m], bfr[n], acc[m][n]);
        __builtin_amdgcn_s_setprio(0);
        __builtin_amdgcn_sched_barrier(0);
        __builtin_amdgcn_s_barrier();

        // phase 1: kk0, mf 4-7
#pragma unroll
        for (int m = 0; m < 4; ++m) afr[m] = *(const bf16x8*)(Lb + 0 * RSZ + aoff[4 + m]);
        if (t + 2 < T) stage(2, t + 2);
        __builtin_amdgcn_s_barrier();
        __builtin_amdgcn_s_setprio(1);
#pragma unroll
        for (int n = 0; n < 4; ++n)
#pragma unroll
            for (int m = 0; m < 4; ++m)
                acc[4 + m][n] = mfma16(afr[m], bfr[n], acc[4 + m][n]);
        __builtin_amdgcn_s_setprio(0);
        __builtin_amdgcn_sched_barrier(0);
        if (t < T - 2)       { asm volatile("s_waitcnt vmcnt(10)" ::: "memory"); }
        else if (t == T - 2) { asm volatile("s_waitcnt vmcnt(8)"  ::: "memory"); }
        else                 { asm volatile("s_waitcnt vmcnt(0)"  ::: "memory"); }
        __builtin_amdgcn_s_barrier();

        // phase 2: kk1, mf 0-3
#pragma unroll
        for (int n = 0; n < 4; ++n) bfr[n] = *(const bf16x8*)(Lb + 3 * RSZ + boff[n]);
#pragma unroll
        for (int m = 0; m < 4; ++m) afr[m] = *(const bf16x8*)(Lb + 1 * RSZ + aoff[m]);
        if (t + 2 < T) stage(0, t + 2);
        __builtin_amdgcn_s_barrier();
        __builtin_amdgcn_s_setprio(1);
#pragma unroll
        for (int n = 0; n < 4; ++n)
#pragma unroll
            for (int m = 0; m < 4; ++m)
                acc[m][n] = mfma16(afr[m], bfr[n], acc[m][n]);
        __builtin_amdgcn_s_setprio(0);
        __builtin_amdgcn_sched_barrier(0);
        __builtin_amdgcn_s_barrier();

        // phase 3: kk1, mf 4-7
#pragma unroll
        for (int m = 0; m < 4; ++m) afr[m] = *(const bf16x8*)(Lb + 1 * RSZ + aoff[4 + m]);
        if (t + 2 < T) stage(3, t + 2);
        __builtin_amdgcn_s_barrier();
        __builtin_amdgcn_s_setprio(1);
#pragma unroll
        for (int n = 0; n < 4; ++n)
#pragma unroll
            for (int m = 0; m < 4; ++m)
                acc[4 + m][n] = mfma16(afr[m], bfr[n], acc[4 + m][n]);
        __builtin_amdgcn_s_setprio(0);
        __builtin_amdgcn_sched_barrier(0);
        if (t + 1 < T) {
            if (t + 2 < T) { asm volatile("s_waitcnt vmcnt(10)" ::: "memory"); }
            else           { asm volatile("s_waitcnt vmcnt(4)"  ::: "memory"); }
        }
        __builtin_amdgcn_s_barrier();
    }

#pragma unroll
    for (int m = 0; m < 8; ++m) {
        const int rowb = m0 + wr * 128 + m * 16 + kq * 4;
#pragma unroll
        for (int n = 0; n < 4; ++n) {
            const int col = n0 + wc * 64 + n * 16 + l15;
#pragma unroll
            for (int r = 0; r < 4; ++r) {
                float v = acc[m][n][r];
                const size_t idx = (size_t)(rowb + r) * Ncol + col;
                if constexpr (EPI == 0) {
                    Cf[zoff + idx] = v;
                } else if constexpr (EPI == 2) {
                    Cf[idx] = 1.f / (1.f + __expf(-v));
                } else {
                    Ch[idx] = f2h(v);
                }
            }
        }
    }
}

// ---------------------------------------------------------------- converts
__global__ __launch_bounds__(256)
void convert_f16(const float* __restrict__ in, unsigned short* __restrict__ hi, size_t n)
{
    size_t i = ((size_t)blockIdx.x * blockDim.x + threadIdx.x) * 4;
    const size_t stride = (size_t)gridDim.x * blockDim.x * 4;
    for (; i < n; i += stride) {
        float4 v = *(const float4*)(in + i);
        us4 h;
        h.x = f2h(v.x); h.y = f2h(v.y); h.z = f2h(v.z); h.w = f2h(v.w);
        *(us4*)(hi + i) = h;
    }
}

// fp32 [R][C] -> fp16 [C][R]; optional v -= cvec[col]*csc
template<bool CSUB>
__global__ __launch_bounds__(256)
void transpose_cvt(const float* __restrict__ in, unsigned short* __restrict__ hi,
                   const float* __restrict__ cvec, float csc, int R, int C)
{
    __shared__ float tile[32][33];
    const int t = threadIdx.x, tx = t & 31, ty = t >> 5;
    const int c0 = blockIdx.x * 32, r0 = blockIdx.y * 32;
#pragma unroll
    for (int i = 0; i < 4; ++i)
        tile[ty + 8 * i][tx] = in[(size_t)(r0 + ty + 8 * i) * C + c0 + tx];
    __syncthreads();
#pragma unroll
    for (int i = 0; i < 4; ++i) {
        const int col = c0 + ty + 8 * i;
        float v = tile[tx][ty + 8 * i];
        if (CSUB) v -= cvec[col] * csc;
        hi[(size_t)col * R + r0 + tx] = f2h(v);
    }
}

// ---------------------------------------------------------------- splitK reduces
// RED: 0 = tanh(s+ba[col]) -> fp16 ; 3 = fp16
template<int RED>
__global__ __launch_bounds__(256)
void reduce_splitk(const float* __restrict__ P, size_t seg,
                   const float* __restrict__ ba, int Ncol,
                   unsigned short* __restrict__ outh)
{
    const size_t i = ((size_t)blockIdx.x * blockDim.x + threadIdx.x) * 4;
    float4 a = *(const float4*)(P + i);
    float4 b = *(const float4*)(P + seg + i);
    float4 c = *(const float4*)(P + 2 * seg + i);
    float4 d = *(const float4*)(P + 3 * seg + i);
    float s0 = a.x + b.x + c.x + d.x;
    float s1 = a.y + b.y + c.y + d.y;
    float s2 = a.z + b.z + c.z + d.z;
    float s3 = a.w + b.w + c.w + d.w;

    if constexpr (RED == 0) {
        const int col = (int)(i % (size_t)Ncol);
        us4 h;
        h.x = f2h(tanhf(s0 + ba[col + 0]));
        h.y = f2h(tanhf(s1 + ba[col + 1]));
        h.z = f2h(tanhf(s2 + ba[col + 2]));
        h.w = f2h(tanhf(s3 + ba[col + 3]));
        *(us4*)(outh + i) = h;
    } else {
        us4 h;
        h.x = f2h(s0); h.y = f2h(s1); h.z = f2h(s2); h.w = f2h(s3);
        *(us4*)(outh + i) = h;
    }
}

// splitK reduce (f32 out) + fused column-sum partials (atomicAdd into cvec).
// 16 rows x 512 cols per block; thread t owns one col4 group across all 16 rows.
__global__ __launch_bounds__(256)
void reduce1_colsum(const float* __restrict__ P, size_t seg,
                    float* __restrict__ outf, float* __restrict__ cvec)
{
    const size_t base = (size_t)blockIdx.x * 8192;   // 16 rows x 512
    const int t = threadIdx.x;
    float c0 = 0.f, c1 = 0.f, c2 = 0.f, c3 = 0.f;
#pragma unroll
    for (int i = 0; i < 8; ++i) {
        const int flat = i * 256 + t;                // float4 units
        const size_t idx = base + (size_t)flat * 4;
        float4 a = *(const float4*)(P + idx);
        float4 b = *(const float4*)(P + seg + idx);
        float4 c = *(const float4*)(P + 2 * seg + idx);
        float4 d = *(const float4*)(P + 3 * seg + idx);
        float4 o;
        o.x = a.x + b.x + c.x + d.x;
        o.y = a.y + b.y + c.y + d.y;
        o.z = a.z + b.z + c.z + d.z;
        o.w = a.w + b.w + c.w + d.w;
        *(float4*)(outf + idx) = o;
        c0 += o.x; c1 += o.y; c2 += o.z; c3 += o.w;
    }
    const int col = (t & 127) * 4;                   // same col group for all i
    atomicAdd(&cvec[col + 0], c0);
    atomicAdd(&cvec[col + 1], c1);
    atomicAdd(&cvec[col + 2], c2);
    atomicAdd(&cvec[col + 3], c3);
}

// Fused: T = sum(partials)*scale + rs[row]*cv[col]*invN, then row softmax;
// writes Zp f32 (final output) + transposed fp16 [512][N]. 16 rows per block.
__global__ __launch_bounds__(256)
void reduce_softmax16_t(const float* __restrict__ P, size_t seg,
                        const float* __restrict__ rs, const float* __restrict__ cv,
                        float scale, float invN,
                        float* __restrict__ Zp, unsigned short* __restrict__ zt, int N)
{
    __shared__ float s[16][513];
    __shared__ float rsv[16];
    const int t = threadIdx.x, lane = t & 63, wid = t >> 6;
    const int r0 = blockIdx.x * 16;
    if (t < 16) rsv[t] = rs[r0 + t];
    __syncthreads();

    const size_t base = (size_t)r0 * 512;
#pragma unroll
    for (int i = 0; i < 8; ++i) {
        const int flat = i * 256 + t;                // float4 units, 0..2047
        const int row = flat >> 7;
        const int c4 = (flat & 127) * 4;
        const size_t idx = base + (size_t)flat * 4;
        float4 a = *(const float4*)(P + idx);
        float4 b = *(const float4*)(P + seg + idx);
        float4 c = *(const float4*)(P + 2 * seg + idx);
        float4 d = *(const float4*)(P + 3 * seg + idx);
        const float rr = rsv[row] * invN;
        s[row][c4 + 0] = (a.x + b.x + c.x + d.x) * scale + rr * cv[c4 + 0];
        s[row][c4 + 1] = (a.y + b.y + c.y + d.y) * scale + rr * cv[c4 + 1];
        s[row][c4 + 2] = (a.z + b.z + c.z + d.z) * scale + rr * cv[c4 + 2];
        s[row][c4 + 3] = (a.w + b.w + c.w + d.w) * scale + rr * cv[c4 + 3];
    }
    __syncthreads();

#pragma unroll
    for (int rr = 0; rr < 4; ++rr) {
        const int row = wid * 4 + rr;
        float vals[8];
        float m = -3.402823466e38f;
#pragma unroll
        for (int j = 0; j < 8; ++j) { vals[j] = s[row][lane * 8 + j]; m = fmaxf(m, vals[j]); }
#pragma unroll
        for (int o = 32; o > 0; o >>= 1) m = fmaxf(m, __shfl_xor(m, o));
        float sum = 0.f;
#pragma unroll
        for (int j = 0; j < 8; ++j) { vals[j] = __expf(vals[j] - m); sum += vals[j]; }
#pragma unroll
        for (int o = 32; o > 0; o >>= 1) sum += __shfl_xor(sum, o);
        const float inv = 1.f / sum;
        float4 o1, o2;
        o1.x = vals[0] * inv; o1.y = vals[1] * inv; o1.z = vals[2] * inv; o1.w = vals[3] * inv;
        o2.x = vals[4] * inv; o2.y = vals[5] * inv; o2.z = vals[6] * inv; o2.w = vals[7] * inv;
        s[row][lane * 8 + 0] = o1.x; s[row][lane * 8 + 1] = o1.y;
        s[row][lane * 8 + 2] = o1.z; s[row][lane * 8 + 3] = o1.w;
        s[row][lane * 8 + 4] = o2.x; s[row][lane * 8 + 5] = o2.y;
        s[row][lane * 8 + 6] = o2.z; s[row][lane * 8 + 7] = o2.w;
        *(float4*)(Zp + (size_t)(r0 + row) * 512 + lane * 8) = o1;
        *(float4*)(Zp + (size_t)(r0 + row) * 512 + lane * 8 + 4) = o2;
    }
    __syncthreads();

#pragma unroll
    for (int cc = 0; cc < 2; ++cc) {
        const int col = t * 2 + cc;
        unsigned short tmp[16];
#pragma unroll
        for (int row = 0; row < 16; ++row) tmp[row] = f2h(s[row][col]);
#pragma unroll
        for (int q = 0; q < 4; ++q)
            *(us4*)(zt + (size_t)col * N + r0 + q * 4) = *(us4*)&tmp[q * 4];
    }
}

// ---------------------------------------------------------------- reductions
__device__ inline float blockReduceMax(float v, float* sred)
{
    for (int o = 32; o > 0; o >>= 1) v = fmaxf(v, __shfl_down(v, o));
    const int lane = threadIdx.x & 63, wid = threadIdx.x >> 6;
    if (lane == 0) sred[wid] = v;
    __syncthreads();
    if (threadIdx.x == 0) {
        float m = sred[0];
        for (int w = 1; w < 4; ++w) m = fmaxf(m, sred[w]);
        sred[0] = m;
    }
    __syncthreads();
    float r = sred[0];
    __syncthreads();
    return r;
}

__device__ inline float blockReduceSum(float v, float* sred)
{
    for (int o = 32; o > 0; o >>= 1) v += __shfl_down(v, o);
    const int lane = threadIdx.x & 63, wid = threadIdx.x >> 6;
    if (lane == 0) sred[wid] = v;
    __syncthreads();
    if (threadIdx.x == 0) {
        float m = sred[0];
        for (int w = 1; w < 4; ++w) m += sred[w];
        sred[0] = m;
    }
    __syncthreads();
    float r = sred[0];
    __syncthreads();
    return r;
}

// A2 = Uh * softmax_rows(L fp16) -> fp16 (x1024) + rowsum(A2); one block per row
__global__ __launch_bounds__(256)
void softmax_mul_f16s(const unsigned short* __restrict__ Lrow,
                      const unsigned short* __restrict__ Uh,
                      unsigned short* __restrict__ hi, float* __restrict__ rowsum, int Ncols)
{
    __shared__ float srow[8192];
    __shared__ float sred[8];
    const int t = threadIdx.x;
    const size_t base = (size_t)blockIdx.x * Ncols;

    float lmax = -3.402823466e38f;
    for (int c = t * 4; c < Ncols; c += 1024) {
        us4 lv = *(const us4*)(Lrow + base + c);
        float4 v;
        v.x = h2f(lv.x); v.y = h2f(lv.y); v.z = h2f(lv.z); v.w = h2f(lv.w);
        *(float4*)&srow[c] = v;
        lmax = fmaxf(lmax, fmaxf(fmaxf(v.x, v.y), fmaxf(v.z, v.w)));
    }
    const float rmax = blockReduceMax(lmax, sred);

    float lsum = 0.f;
    for (int c = t * 4; c < Ncols; c += 1024) {
        float4 v = *(float4*)&srow[c];
        v.x = __expf(v.x - rmax);
        v.y = __expf(v.y - rmax);
        v.z = __expf(v.z - rmax);
        v.w = __expf(v.w - rmax);
        *(float4*)&srow[c] = v;
        lsum += v.x + v.y + v.z + v.w;
    }
    const float rsum = blockReduceSum(lsum, sred);
    const float inv = 1.f / rsum;

    float a2sum = 0.f;
    for (int c = t * 4; c < Ncols; c += 1024) {
        float4 e = *(float4*)&srow[c];
        us4 u = *(const us4*)(Uh + base + c);
        float a0 = h2f(u.x) * e.x * inv, a1 = h2f(u.y) * e.y * inv;
        float a2 = h2f(u.z) * e.z * inv, a3 = h2f(u.w) * e.w * inv;
        a2sum += a0 + a1 + a2 + a3;
        us4 h;
        h.x = f2h(a0 * 1024.f);
        h.y = f2h(a1 * 1024.f);
        h.z = f2h(a2 * 1024.f);
        h.w = f2h(a3 * 1024.f);
        *(us4*)(hi + base + c) = h;
    }
    const float rssum = blockReduceSum(a2sum, sred);
    if (t == 0) rowsum[blockIdx.x] = rssum;
}

// ---------------------------------------------------------------- old engine (fallback)
template<int FM, int WM, int WN, int EPI>
__global__ __launch_bounds__(WM * WN * 64)
void gemm_mfma(const unsigned short* __restrict__ Ahi,
               const unsigned short* __restrict__ Bh, float* __restrict__ Cf,
               unsigned short* __restrict__ Ch,
               int M, int Ncol, int Kdim)
{
    constexpr int NWAVES = WM * WN;
    constexpr int BM = WM * FM * 16;
    constexpr int BN = WN * 64;
    constexpr int ABYTES = BM * 64;
    constexpr int BBYTES = BN * 64;
    constexpr int LDSB = ABYTES + BBYTES;
    constexpr int CPW = LDSB / 1024 / NWAVES;

    __shared__ __align__(1024) char lds[2][LDSB];

    const int t = threadIdx.x;
    const int w = t >> 6, lane = t & 63;

    const int gx = gridDim.x;
    const int nwg = gx * gridDim.y;
    const int lid = blockIdx.y * gx + blockIdx.x;
    const int tl = (lid & 7) * (nwg >> 3) + (lid >> 3);
    const int m0 = (tl / gx) * BM, n0 = (tl % gx) * BN;

    const int kseg = Kdim / gridDim.z;
    const int kbeg = blockIdx.z * kseg;
    const int ksteps = kseg >> 5;
    const size_t zoff = (size_t)blockIdx.z * ((size_t)M * Ncol);

    const int wr = w / WN, wc = w % WN;
    const int l15 = lane & 15, kq = lane >> 4;

    const char* gsrc[CPW];
    int lofs[CPW];
#pragma unroll
    for (int c = 0; c < CPW; ++c) {
        const int boff = (w * CPW + c) * 1024;
        lofs[c] = boff;
        const int poff = swz(boff + lane * 16);
        const unsigned short* mat;
        int moff, rbase;
        if (poff < ABYTES) { mat = Ahi; moff = poff;          rbase = m0; }
        else               { mat = Bh;  moff = poff - ABYTES; rbase = n0; }
        gsrc[c] = (const char*)(mat + (size_t)(rbase + (moff >> 6)) * Kdim + kbeg) + (moff & 63);
    }

    int aoffS[FM], boffS[4];
#pragma unroll
    for (int m = 0; m < FM; ++m)
        aoffS[m] = swz((wr * (FM * 16) + m * 16 + l15) * 64 + kq * 16);
#pragma unroll
    for (int n = 0; n < 4; ++n)
        boffS[n] = swz(ABYTES + (wc * 64 + n * 16 + l15) * 64 + kq * 16);

    f32x4 acc[FM][4];
#pragma unroll
    for (int m = 0; m < FM; ++m)
#pragma unroll
        for (int n = 0; n < 4; ++n)
            acc[m][n] = (f32x4)(0.f);

    auto stage = [&](int buf) {
#pragma unroll
        for (int c = 0; c < CPW; ++c) {
            gload_lds16(gsrc[c], &lds[buf][lofs[c]]);
            gsrc[c] += 64;
        }
    };

    stage(0);
    __syncthreads();

    int cur = 0;
    for (int ks = 0; ks < ksteps; ++ks) {
        if (ks + 1 < ksteps) stage(cur ^ 1);

        const char* Lb = lds[cur];
        bf16x8 ah[FM], bb[4];
#pragma unroll
        for (int m = 0; m < FM; ++m)
            ah[m] = *(const bf16x8*)(Lb + aoffS[m]);
#pragma unroll
        for (int n = 0; n < 4; ++n)
            bb[n] = *(const bf16x8*)(Lb + boffS[n]);

        __builtin_amdgcn_s_setprio(1);
#pragma unroll
        for (int n = 0; n < 4; ++n)
#pragma unroll
            for (int m = 0; m < FM; ++m)
                acc[m][n] = mfma16(ah[m], bb[n], acc[m][n]);
        __builtin_amdgcn_s_setprio(0);

        __syncthreads();
        cur ^= 1;
    }

#pragma unroll
    for (int m = 0; m < FM; ++m) {
        const int rowb = m0 + wr * (FM * 16) + m * 16 + kq * 4;
#pragma unroll
        for (int n = 0; n < 4; ++n) {
            const int col = n0 + wc * 64 + n * 16 + l15;
#pragma unroll
            for (int r = 0; r < 4; ++r) {
                float v = acc[m][n][r];
                const size_t idx = (size_t)(rowb + r) * Ncol + col;
                if constexpr (EPI == 0) {
                    Cf[zoff + idx] = v;
                } else if constexpr (EPI == 2) {
                    Cf[idx] = 1.f / (1.f + __expf(-v));
                } else {
                    Ch[idx] = f2h(v);
                }
            }
        }
    }
}

// ---------------------------------------------------------------- fp32 fallback
template<int EPI, bool TB>
__global__ __launch_bounds__(256)
void gemm_f32(const float* __restrict__ A, const float* __restrict__ B,
              const float* __restrict__ bias, float* __restrict__ C,
              int M, int Ncol, int Kdim)
{
    constexpr int FBM = 128, FBN = 128, FBK = 8;
    __shared__ float As[FBK][FBM];
    __shared__ float Bs[FBK][FBN];
    const int t  = threadIdx.x;
    const int tx = t & 15, ty = t >> 4;
    const int m0 = blockIdx.y * FBM, n0 = blockIdx.x * FBN;

    const int arow  = t >> 1;
    const int acol4 = (t & 1) * 4;
    const int brow  = t >> 5;
    const int bcol4 = (t & 31) * 4;

    float acc[8][8];
#pragma unroll
    for (int i = 0; i < 8; ++i)
#pragma unroll
        for (int j = 0; j < 8; ++j) acc[i][j] = 0.f;

    const float* Aptr = A + (size_t)(m0 + arow) * Kdim + acol4;
    const float* Bptr;
    if (TB) Bptr = B + (size_t)(n0 + arow) * Kdim + acol4;
    else    Bptr = B + (size_t)brow * Ncol + n0 + bcol4;

    float4 av = *(const float4*)(Aptr);
    float4 bv = *(const float4*)(Bptr);

    for (int k0 = 0; k0 < Kdim; k0 += FBK) {
        As[acol4 + 0][arow] = av.x;
        As[acol4 + 1][arow] = av.y;
        As[acol4 + 2][arow] = av.z;
        As[acol4 + 3][arow] = av.w;
        if (TB) {
            Bs[acol4 + 0][arow] = bv.x;
            Bs[acol4 + 1][arow] = bv.y;
            Bs[acol4 + 2][arow] = bv.z;
            Bs[acol4 + 3][arow] = bv.w;
        } else {
            *(float4*)&Bs[brow][bcol4] = bv;
        }
        __syncthreads();

        if (k0 + FBK < Kdim) {
            av = *(const float4*)(Aptr + (k0 + FBK));
            if (TB) bv = *(const float4*)(Bptr + (k0 + FBK));
            else    bv = *(const float4*)(Bptr + (size_t)(k0 + FBK) * Ncol);
        }

#pragma unroll
        for (int kk = 0; kk < FBK; ++kk) {
            float a[8], b[8];
            *(float4*)&a[0] = *(const float4*)&As[kk][ty * 4];
            *(float4*)&a[4] = *(const float4*)&As[kk][64 + ty * 4];
            *(float4*)&b[0] = *(const float4*)&Bs[kk][tx * 4];
            *(float4*)&b[4] = *(const float4*)&Bs[kk][64 + tx * 4];
#pragma unroll
            for (int i = 0; i < 8; ++i)
#pragma unroll
                for (int j = 0; j < 8; ++j)
                    acc[i][j] = fmaf(a[i], b[j], acc[i][j]);
        }
        __syncthreads();
    }

#pragma unroll
    for (int ib = 0; ib < 2; ++ib) {
#pragma unroll
        for (int ii = 0; ii < 4; ++ii) {
            const int i = ib * 4 + ii;
            const size_t row = (size_t)(m0 + ib * 64 + ty * 4 + ii);
            float* crow = C + row * (size_t)Ncol;
#pragma unroll
            for (int jb = 0; jb < 2; ++jb) {
                const int col0 = n0 + jb * 64 + tx * 4;
                float4 v;
                v.x = acc[i][jb * 4 + 0];
                v.y = acc[i][jb * 4 + 1];
                v.z = acc[i][jb * 4 + 2];
                v.w = acc[i][jb * 4 + 3];
                if (EPI == 1) {
                    v.x = tanhf(v.x + bias[col0 + 0]);
                    v.y = tanhf(v.y + bias[col0 + 1]);
                    v.z = tanhf(v.z + bias[col0 + 2]);
                    v.w = tanhf(v.w + bias[col0 + 3]);
                } else if (EPI == 2) {
                    v.x = 1.f / (1.f + __expf(-v.x));
                    v.y = 1.f / (1.f + __expf(-v.y));
                    v.z = 1.f / (1.f + __expf(-v.z));
                    v.w = 1.f / (1.f + __expf(-v.w));
                }
                *(float4*)(crow + col0) = v;
            }
        }
    }
}

__global__ __launch_bounds__(256)
void softmax_mul_f32(float* buf, const float* __restrict__ U, int Ncols)
{
    __shared__ float srow[8192];
    __shared__ float sred[8];
    const int t = threadIdx.x;
    const size_t base = (size_t)blockIdx.x * Ncols;

    float lmax = -3.402823466e38f;
    for (int c = t * 4; c < Ncols; c += 1024) {
        float4 v = *(const float4*)(buf + base + c);
        *(float4*)&srow[c] = v;
        lmax = fmaxf(lmax, fmaxf(fmaxf(v.x, v.y), fmaxf(v.z, v.w)));
    }
    const float rmax = blockReduceMax(lmax, sred);

    float lsum = 0.f;
    for (int c = t * 4; c < Ncols; c += 1024) {
        float4 v = *(float4*)&srow[c];
        v.x = __expf(v.x - rmax);
        v.y = __expf(v.y - rmax);
        v.z = __expf(v.z - rmax);
        v.w = __expf(v.w - rmax);
        *(float4*)&srow[c] = v;
        lsum += v.x + v.y + v.z + v.w;
    }
    const float rsum = blockReduceSum(lsum, sred);
    const float inv = 1.f / rsum;

    for (int c = t * 4; c < Ncols; c += 1024) {
        float4 e = *(float4*)&srow[c];
        float4 u = *(const float4*)(U + base + c);
        float4 o;
        o.x = u.x * e.x * inv;
        o.y = u.y * e.y * inv;
        o.z = u.z * e.z * inv;
        o.w = u.w * e.w * inv;
        *(float4*)(buf + base + c) = o;
    }
}

__global__ __launch_bounds__(256)
void softmax_inplace_small(float* buf, int D)
{
    __shared__ float sred[8];
    const int t = threadIdx.x;
    const size_t base = (size_t)blockIdx.x * D;
    float2 v = *(float2*)(buf + base + t * 2);
    const float rmax = blockReduceMax(fmaxf(v.x, v.y), sred);
    const float e0 = __expf(v.x - rmax);
    const float e1 = __expf(v.y - rmax);
    const float rsum = blockReduceSum(e0 + e1, sred);
    const float inv = 1.f / rsum;
    float2 o;
    o.x = e0 * inv;
    o.y = e1 * inv;
    *(float2*)(buf + base + t * 2) = o;
}

// ---------------------------------------------------------------- launch
extern "C" void kernel_launch(void* const* d_in, const int* in_sizes, int n_in,
                              void* d_out, int out_size, void* d_ws, size_t ws_size,
                              hipStream_t stream)
{
    const float* U  = (const float*)d_in[0];
    const float* X  = (const float*)d_in[1];
    const float* H1 = (const float*)d_in[2];
    const float* W0 = (const float*)d_in[3];
    const float* W1 = (const float*)d_in[4];
    const float* Wa = (const float*)d_in[5];
    const float* ba = (const float*)d_in[6];
    const int D = in_sizes[6];
    const int N = (int)((long long)in_sizes[2] / D);
    const size_t NN = (size_t)N * N, ND = (size_t)N * D;

    float* Xp = (float*)d_out;          // [N,N] final; scratch for L (as fp16)
    float* Zp = Xp + NN;                // [N,D] final Z

    char* p = (char*)d_ws;
    auto alloc = [&](size_t bytes) { char* r = p; p += (bytes + 255) & ~(size_t)255; return r; };
    unsigned short* wa_h  = (unsigned short*)alloc(ND * 2);
    unsigned short* h1_h  = (unsigned short*)alloc(ND * 2);
    unsigned short* k_h   = (unsigned short*)alloc(ND * 2);
    unsigned short* w0t_h = (unsigned short*)alloc(ND * 2);
    unsigned short* vbt   = (unsigned short*)alloc(ND * 2);
    unsigned short* zt_h  = (unsigned short*)alloc(ND * 2);
    unsigned short* uz_h  = (unsigned short*)alloc(ND * 2);
    unsigned short* w1t_h = (unsigned short*)alloc(ND * 2);
    float*          xw0f  = (float*)alloc(ND * 4);
    float*          cvec  = (float*)alloc((size_t)D * 4);
    float*          rsum  = (float*)alloc((size_t)N * 4);
    float*          Pp    = (float*)alloc(ND * 4 * 4);        // splitK=4 partials
    unsigned short* Uh    = (unsigned short*)alloc(NN * 2);
    unsigned short* Xh    = (unsigned short*)alloc(NN * 2);
    const size_t need = (size_t)(p - (char*)d_ws);

    dim3 blk(256), blk512(512);

    if (N == 8192 && D == 512 && ws_size >= need) {
        constexpr int LDS8P = 131072;
        bool ok8p = true;
        ok8p &= hipFuncSetAttribute((const void*)gemm8p<0>,
                    hipFuncAttributeMaxDynamicSharedMemorySize, LDS8P) == hipSuccess;
        ok8p &= hipFuncSetAttribute((const void*)gemm8p<2>,
                    hipFuncAttributeMaxDynamicSharedMemorySize, LDS8P) == hipSuccess;
        ok8p &= hipFuncSetAttribute((const void*)gemm8p<3>,
                    hipFuncAttributeMaxDynamicSharedMemorySize, LDS8P) == hipSuccess;

        unsigned short* Lh = (unsigned short*)Xp;
        const dim3 gSlim8(D / 256, N / 256, 4);    // (2,32,4) splitK slims
        const dim3 gBig8(N / 256, N / 256);        // (32,32) bigs
        const dim3 gSlimK(D / 128, N / 128, 4);
        const dim3 gBig(N / 256, N / 128);
        const dim3 gT(D / 32, N / 32);
        const dim3 gTw1(N / 32, D / 32);
        const dim3 gRed((unsigned)(ND / 1024));    // elementwise reduces
        const dim3 gRow(N / 16);                   // 16-rows-per-block kernels
        const int cgrid = 4096;
        const float invN = 1.0f / (float)N;
        unsigned short* nullw = nullptr;
        const float* nullf = nullptr;

        auto slimGemm = [&](const unsigned short* A_, const unsigned short* B_, float* C_) {
            if (ok8p)
                hipLaunchKernelGGL((gemm8p<0>), gSlim8, blk512, LDS8P, stream,
                                   A_, B_, C_, nullw, N, D, N);
            else
                hipLaunchKernelGGL((gemm_mfma<4, 2, 2, 0>), gSlimK, blk, 0, stream,
                                   A_, B_, C_, nullw, N, D, N);
        };

        // U, Wa -> fp16
        hipLaunchKernelGGL(convert_f16, dim3(cgrid), blk, 0, stream, U, Uh, NN);
        hipLaunchKernelGGL(convert_f16, dim3(1024), blk, 0, stream, Wa, wa_h, ND);
        // K = U @ Wa^T (splitK) -> reduce w/ tanh+bias -> k fp16
        slimGemm(Uh, wa_h, Pp);
        hipLaunchKernelGGL((reduce_splitk<0>), gRed, blk, 0, stream, Pp, ND, ba, D, k_h);
        hipLaunchKernelGGL(convert_f16, dim3(1024), blk, 0, stream, H1, h1_h, ND);
        // L = K @ H1^T -> fp16 Lh
        if (ok8p)
            hipLaunchKernelGGL((gemm8p<3>), gBig8, blk512, LDS8P, stream,
                               k_h, h1_h, (float*)nullptr, Lh, N, N, D);
        else
            hipLaunchKernelGGL((gemm_mfma<4, 2, 4, 3>), gBig, blk512, 0, stream,
                               k_h, h1_h, (float*)nullptr, Lh, N, N, D);
        // X -> fp16
        hipLaunchKernelGGL(convert_f16, dim3(cgrid), blk, 0, stream, X, Xh, NN);
        hipLaunchKernelGGL((transpose_cvt<false>), gT, blk, 0, stream, W0, w0t_h, nullf, 0.f, N, D);
        // XW0 = X @ W0 (splitK) -> fused reduce + raw colsum
        slimGemm(Xh, w0t_h, Pp);
        hipMemsetAsync(cvec, 0, (size_t)D * 4, stream);
        hipLaunchKernelGGL(reduce1_colsum, gRow, blk, 0, stream, Pp, ND, xw0f, cvec);
        // V = (XW0 - c)^T -> fp16 [D][N]   (c = cvec_raw * invN)
        hipLaunchKernelGGL((transpose_cvt<true>), gT, blk, 0, stream, xw0f, vbt, cvec, invN, N, D);
        // A2s = 1024 * Uh * softmax(L fp16) -> fp16 + rowsum
        hipLaunchKernelGGL(softmax_mul_f16s, dim3(N), blk, 0, stream, Lh, Uh, Xh, rsum, N);
        // T = A2s @ V (splitK); fused: reduce + affine + softmax + transpose
        slimGemm(Xh, vbt, Pp);
        hipLaunchKernelGGL(reduce_softmax16_t, gRow, blk, 0, stream,
                           Pp, ND, rsum, cvec, 1.0f / 1024.f, invN, Zp, zt_h, N);
        // UZ = U @ Z (splitK) -> reduce -> uz fp16
        slimGemm(Uh, zt_h, Pp);
        hipLaunchKernelGGL((reduce_splitk<3>), gRed, blk, 0, stream, Pp, ND, nullf, D, uz_h);
        hipLaunchKernelGGL((transpose_cvt<false>), gTw1, blk, 0, stream, W1, w1t_h, nullf, 0.f, D, N);
        // Xp = sigmoid(UZ @ W1)
        if (ok8p)
            hipLaunchKernelGGL((gemm8p<2>), gBig8, blk512, LDS8P, stream,
                               uz_h, w1t_h, Xp, nullw, N, N, D);
        else
            hipLaunchKernelGGL((gemm_mfma<4, 2, 4, 2>), gBig, blk512, 0, stream,
                               uz_h, w1t_h, Xp, nullw, N, N, D);
    } else {
        // -------- fp32 fallback
        float* bufA = (float*)d_ws;
        dim3 gD(D / 128, N / 128);
        dim3 gN(N / 128, N / 128);
        hipLaunchKernelGGL((gemm_f32<1, true>),  gD, blk, 0, stream, U,    Wa, ba,      bufA, N, D, N);
        hipLaunchKernelGGL((gemm_f32<0, true>),  gN, blk, 0, stream, bufA, H1, nullptr, Xp,   N, N, D);
        hipLaunchKernelGGL(softmax_mul_f32, dim3(N), blk, 0, stream, Xp, U, N);
        hipLaunchKernelGGL((gemm_f32<0, false>), gD, blk, 0, stream, X,    W0, nullptr, bufA, N, D, N);
        hipLaunchKernelGGL((gemm_f32<0, false>), gD, blk, 0, stream, Xp,   bufA, nullptr, Zp, N, D, N);
        hipLaunchKernelGGL(softmax_inplace_small, dim3(N), blk, 0, stream, Zp, D);
        hipLaunchKernelGGL((gemm_f32<0, false>), gD, blk, 0, stream, U,    Zp, nullptr, bufA, N, D, N);
        hipLaunchKernelGGL((gemm_f32<2, false>), gN, blk, 0, stream, bufA, W1, nullptr, Xp,  N, N, D);
    }
}

// Round 11
// 912.886 us; speedup vs baseline: 1.0733x; 1.0733x over previous
//
#include <hip/hip_runtime.h>
#include <math.h>

// GCNNet: N=8192, D=512. Round-9 base (913 us) + ONE change: the T-chain
// reduce+affine+softmax+transpose is fused into reduce_softmax4_t with
// 4 rows/block (2048 blocks, register softmax) — parallelism preserved.
// GEMM engine: 256x256-tile 8-wave 8-phase schedule (K-half regions, counted
// vmcnt, raw s_barrier, 128KB dynamic LDS); round-8 engine as fallback.

typedef __attribute__((ext_vector_type(8))) short bf16x8;     // raw 16B container
typedef __attribute__((ext_vector_type(8))) _Float16 f16x8;
typedef __attribute__((ext_vector_type(4))) float f32x4;
typedef __attribute__((ext_vector_type(4))) unsigned short us4;

__device__ __forceinline__ unsigned short f2h(float x) {
    _Float16 h = (_Float16)x;
    return __builtin_bit_cast(unsigned short, h);
}
__device__ __forceinline__ float h2f(unsigned short u) {
    return (float)__builtin_bit_cast(_Float16, u);
}

__device__ __forceinline__ void gload_lds16(const char* g, char* l) {
    __builtin_amdgcn_global_load_lds(
        (const __attribute__((address_space(1))) unsigned int*)g,
        (__attribute__((address_space(3))) unsigned int*)l, 16, 0, 0);
}

// XOR bank swizzles (involutions, preserve 16B alignment)
__device__ __forceinline__ int swz(int o) {
    return o ^ (((o >> 7) & 7) << 4);
}
__device__ __forceinline__ int swzk(int o) {
    return o ^ (((o >> 7) & 3) << 4);
}

__device__ __forceinline__ f32x4 mfma16(bf16x8 a, bf16x8 b, f32x4 c) {
    return __builtin_amdgcn_mfma_f32_16x16x32_f16(
        __builtin_bit_cast(f16x8, a), __builtin_bit_cast(f16x8, b), c, 0, 0, 0);
}

// ================================================================ 8-phase GEMM
// A [M,K] fp16 row-major, B [Ncol,K] fp16 row-major. 256x256 tile, 8 waves.
// BK=64 as two K-halves; regions A_k0,A_k1,B_k0,B_k1 (16KB each); dbuf 128KB.
// splitK via gridDim.z. EPI: 0 f32 (+zoff), 2 sigmoid f32, 3 fp16.
template<int EPI>
__global__ __launch_bounds__(512, 1)
void gemm8p(const unsigned short* __restrict__ A, const unsigned short* __restrict__ B,
            float* __restrict__ Cf, unsigned short* __restrict__ Ch,
            int M, int Ncol, int Kdim)
{
    extern __shared__ char lds[];            // 131072 bytes
    constexpr int RSZ = 16384;               // region bytes

    const int tid = threadIdx.x;
    const int w = tid >> 6, lane = tid & 63;
    const int wr = w >> 2, wc = w & 3;       // 2 x 4 wave grid
    const int l15 = lane & 15, kq = lane >> 4;

    const int gx = gridDim.x;
    const int nwg = gx * gridDim.y;
    const int lid = blockIdx.y * gx + blockIdx.x;
    const int tl = (lid & 7) * (nwg >> 3) + (lid >> 3);
    const int m0 = (tl / gx) * 256, n0 = (tl % gx) * 256;

    const int kseg = Kdim / gridDim.z;
    const int kbeg = blockIdx.z * kseg;
    const int T = kseg >> 6;                 // BK = 64
    const size_t zoff = (size_t)blockIdx.z * ((size_t)M * Ncol);

    const int Kb = Kdim * 2;
    const char* gp[4][2];
    {
        const char* Ab = (const char*)A + (size_t)m0 * Kb + (size_t)kbeg * 2;
        const char* Bb = (const char*)B + (size_t)n0 * Kb + (size_t)kbeg * 2;
#pragma unroll
        for (int r = 0; r < 4; ++r) {
            const char* base = (r < 2) ? Ab : Bb;
            const int khalf = r & 1;
#pragma unroll
            for (int j = 0; j < 2; ++j) {
                const int moff = swzk((w * 2 + j) * 1024 + lane * 16);
                gp[r][j] = base + (size_t)(moff >> 6) * Kb + khalf * 64 + (moff & 63);
            }
        }
    }

    auto stage = [&](int r, int tile) {
        char* dst = lds + (tile & 1) * 65536 + r * RSZ + w * 2048;
        gload_lds16(gp[r][0] + (size_t)tile * 128, dst);
        gload_lds16(gp[r][1] + (size_t)tile * 128, dst + 1024);
    };

    int aoff[8], boff[4];
#pragma unroll
    for (int mf = 0; mf < 8; ++mf)
        aoff[mf] = swzk((wr * 128 + mf * 16 + l15) * 64 + kq * 16);
#pragma unroll
    for (int n = 0; n < 4; ++n)
        boff[n] = swzk((wc * 64 + n * 16 + l15) * 64 + kq * 16);

    f32x4 acc[8][4];
#pragma unroll
    for (int m = 0; m < 8; ++m)
#pragma unroll
        for (int n = 0; n < 4; ++n)
            acc[m][n] = (f32x4)(0.f);

    stage(2, 0); stage(0, 0); stage(3, 0); stage(1, 0);
    stage(2, 1); stage(0, 1); stage(3, 1);
    asm volatile("s_waitcnt vmcnt(10)" ::: "memory");
    __builtin_amdgcn_s_barrier();

    for (int t = 0; t < T; ++t) {
        const char* Lb = lds + (t & 1) * 65536;
        bf16x8 bfr[4], afr[4];

        // phase 0: kk0, mf 0-3
#pragma unroll
        for (int n = 0; n < 4; ++n) bfr[n] = *(const bf16x8*)(Lb + 2 * RSZ + boff[n]);
#pragma unroll
        for (int m = 0; m < 4; ++m) afr[m] = *(const bf16x8*)(Lb + 0 * RSZ + aoff[m]);
        if (t + 1 < T) stage(1, t + 1);
        __builtin_amdgcn_s_barrier();
        __builtin_amdgcn_s_setprio(1);
#pragma unroll
        for (int n = 0; n < 4; ++n)
#pragma unroll
            for (int m = 0; m < 4; ++m)
                acc[m][n] = mfma16(afr[m], bfr[n], acc[m][n]);
        __builtin_amdgcn_s_setprio(0);
        __builtin_amdgcn_sched_barrier(0);
        __builtin_amdgcn_s_barrier();

        // phase 1: kk0, mf 4-7
#pragma unroll
        for (int m = 0; m < 4; ++m) afr[m] = *(const bf16x8*)(Lb + 0 * RSZ + aoff[4 + m]);
        if (t + 2 < T) stage(2, t + 2);
        __builtin_amdgcn_s_barrier();
        __builtin_amdgcn_s_setprio(1);
#pragma unroll
        for (int n = 0; n < 4; ++n)
#pragma unroll
            for (int m = 0; m < 4; ++m)
                acc[4 + m][n] = mfma16(afr[m], bfr[n], acc[4 + m][n]);
        __builtin_amdgcn_s_setprio(0);
        __builtin_amdgcn_sched_barrier(0);
        if (t < T - 2)       { asm volatile("s_waitcnt vmcnt(10)" ::: "memory"); }
        else if (t == T - 2) { asm volatile("s_waitcnt vmcnt(8)"  ::: "memory"); }
        else                 { asm volatile("s_waitcnt vmcnt(0)"  ::: "memory"); }
        __builtin_amdgcn_s_barrier();

        // phase 2: kk1, mf 0-3
#pragma unroll
        for (int n = 0; n < 4; ++n) bfr[n] = *(const bf16x8*)(Lb + 3 * RSZ + boff[n]);
#pragma unroll
        for (int m = 0; m < 4; ++m) afr[m] = *(const bf16x8*)(Lb + 1 * RSZ + aoff[m]);
        if (t + 2 < T) stage(0, t + 2);
        __builtin_amdgcn_s_barrier();
        __builtin_amdgcn_s_setprio(1);
#pragma unroll
        for (int n = 0; n < 4; ++n)
#pragma unroll
            for (int m = 0; m < 4; ++m)
                acc[m][n] = mfma16(afr[m], bfr[n], acc[m][n]);
        __builtin_amdgcn_s_setprio(0);
        __builtin_amdgcn_sched_barrier(0);
        __builtin_amdgcn_s_barrier();

        // phase 3: kk1, mf 4-7
#pragma unroll
        for (int m = 0; m < 4; ++m) afr[m] = *(const bf16x8*)(Lb + 1 * RSZ + aoff[4 + m]);
        if (t + 2 < T) stage(3, t + 2);
        __builtin_amdgcn_s_barrier();
        __builtin_amdgcn_s_setprio(1);
#pragma unroll
        for (int n = 0; n < 4; ++n)
#pragma unroll
            for (int m = 0; m < 4; ++m)
                acc[4 + m][n] = mfma16(afr[m], bfr[n], acc[4 + m][n]);
        __builtin_amdgcn_s_setprio(0);
        __builtin_amdgcn_sched_barrier(0);
        if (t + 1 < T) {
            if (t + 2 < T) { asm volatile("s_waitcnt vmcnt(10)" ::: "memory"); }
            else           { asm volatile("s_waitcnt vmcnt(4)"  ::: "memory"); }
        }
        __builtin_amdgcn_s_barrier();
    }

#pragma unroll
    for (int m = 0; m < 8; ++m) {
        const int rowb = m0 + wr * 128 + m * 16 + kq * 4;
#pragma unroll
        for (int n = 0; n < 4; ++n) {
            const int col = n0 + wc * 64 + n * 16 + l15;
#pragma unroll
            for (int r = 0; r < 4; ++r) {
                float v = acc[m][n][r];
                const size_t idx = (size_t)(rowb + r) * Ncol + col;
                if constexpr (EPI == 0) {
                    Cf[zoff + idx] = v;
                } else if constexpr (EPI == 2) {
                    Cf[idx] = 1.f / (1.f + __expf(-v));
                } else {
                    Ch[idx] = f2h(v);
                }
            }
        }
    }
}

// ---------------------------------------------------------------- converts
__global__ __launch_bounds__(256)
void convert_f16(const float* __restrict__ in, unsigned short* __restrict__ hi, size_t n)
{
    size_t i = ((size_t)blockIdx.x * blockDim.x + threadIdx.x) * 4;
    const size_t stride = (size_t)gridDim.x * blockDim.x * 4;
    for (; i < n; i += stride) {
        float4 v = *(const float4*)(in + i);
        us4 h;
        h.x = f2h(v.x); h.y = f2h(v.y); h.z = f2h(v.z); h.w = f2h(v.w);
        *(us4*)(hi + i) = h;
    }
}

// fp32 [R][C] -> fp16 [C][R]; optional per-source-column subtract
template<bool CSUB>
__global__ __launch_bounds__(256)
void transpose_cvt(const float* __restrict__ in, unsigned short* __restrict__ hi,
                   const float* __restrict__ cvec, int R, int C)
{
    __shared__ float tile[32][33];
    const int t = threadIdx.x, tx = t & 31, ty = t >> 5;
    const int c0 = blockIdx.x * 32, r0 = blockIdx.y * 32;
#pragma unroll
    for (int i = 0; i < 4; ++i)
        tile[ty + 8 * i][tx] = in[(size_t)(r0 + ty + 8 * i) * C + c0 + tx];
    __syncthreads();
#pragma unroll
    for (int i = 0; i < 4; ++i) {
        const int col = c0 + ty + 8 * i;
        float v = tile[tx][ty + 8 * i];
        if (CSUB) v -= cvec[col];
        hi[(size_t)col * R + r0 + tx] = f2h(v);
    }
}

// column sums of [Nrows x 512] fp32 (atomic partials)
__global__ __launch_bounds__(256)
void colsum512(const float* __restrict__ in, float* __restrict__ c, int Nrows)
{
    const int t = threadIdx.x;
    const int r0 = blockIdx.x * 16;
    float s0 = 0.f, s1 = 0.f;
    for (int r = 0; r < 16; ++r) {
        const float* row = in + (size_t)(r0 + r) * 512;
        s0 += row[t];
        s1 += row[t + 256];
    }
    atomicAdd(&c[t], s0);
    atomicAdd(&c[t + 256], s1);
}

__global__ void scale_vec(float* __restrict__ c, float s, int n)
{
    const int t = threadIdx.x;
    if (t < n) c[t] *= s;
}

// ---------------------------------------------------------------- splitK reduces
// RED: 0 = tanh(s+ba[col]) -> fp16 ; 1 = f32 ; 3 = fp16
template<int RED>
__global__ __launch_bounds__(256)
void reduce_splitk(const float* __restrict__ P, size_t seg,
                   const float* __restrict__ ba, int Ncol,
                   float* __restrict__ outf, unsigned short* __restrict__ outh)
{
    const size_t i = ((size_t)blockIdx.x * blockDim.x + threadIdx.x) * 4;
    float4 a = *(const float4*)(P + i);
    float4 b = *(const float4*)(P + seg + i);
    float4 c = *(const float4*)(P + 2 * seg + i);
    float4 d = *(const float4*)(P + 3 * seg + i);
    float s0 = a.x + b.x + c.x + d.x;
    float s1 = a.y + b.y + c.y + d.y;
    float s2 = a.z + b.z + c.z + d.z;
    float s3 = a.w + b.w + c.w + d.w;

    if constexpr (RED == 0) {
        const int col = (int)(i % (size_t)Ncol);
        us4 h;
        h.x = f2h(tanhf(s0 + ba[col + 0]));
        h.y = f2h(tanhf(s1 + ba[col + 1]));
        h.z = f2h(tanhf(s2 + ba[col + 2]));
        h.w = f2h(tanhf(s3 + ba[col + 3]));
        *(us4*)(outh + i) = h;
    } else if constexpr (RED == 1) {
        float4 o; o.x = s0; o.y = s1; o.z = s2; o.w = s3;
        *(float4*)(outf + i) = o;
    } else {
        us4 h;
        h.x = f2h(s0); h.y = f2h(s1); h.z = f2h(s2); h.w = f2h(s3);
        *(us4*)(outh + i) = h;
    }
}

// Fused: T = sum(4 splitK planes)*scale + rs[row]*cv[col], row softmax in
// REGISTERS (one wave per row), writes Zp f32 + transposed fp16 [512][N].
// 4 rows/block -> 2048 blocks (parallelism preserved vs elementwise reduce).
__global__ __launch_bounds__(256)
void reduce_softmax4_t(const float* __restrict__ P, size_t seg,
                       const float* __restrict__ rs, const float* __restrict__ cv,
                       float scale,
                       float* __restrict__ Zp, unsigned short* __restrict__ zt, int N)
{
    __shared__ float s[4][516];
    __shared__ float scv[512];
    const int t = threadIdx.x, lane = t & 63, w = t >> 6;
    const int r0 = blockIdx.x * 4;
    if (t < 128) *(float4*)&scv[t * 4] = *(const float4*)(cv + t * 4);
    __syncthreads();

    const int row = r0 + w;
    const float rr = rs[row];
    const size_t base = (size_t)row * 512 + lane * 8;

    float vals[8];
#pragma unroll
    for (int h = 0; h < 2; ++h) {
        float4 a = *(const float4*)(P + base + h * 4);
        float4 b = *(const float4*)(P + seg + base + h * 4);
        float4 c = *(const float4*)(P + 2 * seg + base + h * 4);
        float4 d = *(const float4*)(P + 3 * seg + base + h * 4);
        const int j = h * 4;
        vals[j + 0] = (a.x + b.x + c.x + d.x) * scale + rr * scv[lane * 8 + j + 0];
        vals[j + 1] = (a.y + b.y + c.y + d.y) * scale + rr * scv[lane * 8 + j + 1];
        vals[j + 2] = (a.z + b.z + c.z + d.z) * scale + rr * scv[lane * 8 + j + 2];
        vals[j + 3] = (a.w + b.w + c.w + d.w) * scale + rr * scv[lane * 8 + j + 3];
    }

    float m = -3.402823466e38f;
#pragma unroll
    for (int j = 0; j < 8; ++j) m = fmaxf(m, vals[j]);
#pragma unroll
    for (int o = 32; o > 0; o >>= 1) m = fmaxf(m, __shfl_xor(m, o));
    float sum = 0.f;
#pragma unroll
    for (int j = 0; j < 8; ++j) { vals[j] = __expf(vals[j] - m); sum += vals[j]; }
#pragma unroll
    for (int o = 32; o > 0; o >>= 1) sum += __shfl_xor(sum, o);
    const float inv = 1.f / sum;

    float4 o1, o2;
    o1.x = vals[0] * inv; o1.y = vals[1] * inv; o1.z = vals[2] * inv; o1.w = vals[3] * inv;
    o2.x = vals[4] * inv; o2.y = vals[5] * inv; o2.z = vals[6] * inv; o2.w = vals[7] * inv;
    *(float4*)(Zp + base) = o1;
    *(float4*)(Zp + base + 4) = o2;
    *(float4*)&s[w][lane * 8] = o1;
    *(float4*)&s[w][lane * 8 + 4] = o2;
    __syncthreads();

    // transposed fp16 write: thread t -> cols {2t, 2t+1}; 4 rows = one us4 (8B)
#pragma unroll
    for (int cc = 0; cc < 2; ++cc) {
        const int col = t * 2 + cc;
        us4 h;
        h.x = f2h(s[0][col]);
        h.y = f2h(s[1][col]);
        h.z = f2h(s[2][col]);
        h.w = f2h(s[3][col]);
        *(us4*)(zt + (size_t)col * N + r0) = h;
    }
}

// ---------------------------------------------------------------- reductions
__device__ inline float blockReduceMax(float v, float* sred)
{
    for (int o = 32; o > 0; o >>= 1) v = fmaxf(v, __shfl_down(v, o));
    const int lane = threadIdx.x & 63, wid = threadIdx.x >> 6;
    if (lane == 0) sred[wid] = v;
    __syncthreads();
    if (threadIdx.x == 0) {
        float m = sred[0];
        for (int w = 1; w < 4; ++w) m = fmaxf(m, sred[w]);
        sred[0] = m;
    }
    __syncthreads();
    float r = sred[0];
    __syncthreads();
    return r;
}

__device__ inline float blockReduceSum(float v, float* sred)
{
    for (int o = 32; o > 0; o >>= 1) v += __shfl_down(v, o);
    const int lane = threadIdx.x & 63, wid = threadIdx.x >> 6;
    if (lane == 0) sred[wid] = v;
    __syncthreads();
    if (threadIdx.x == 0) {
        float m = sred[0];
        for (int w = 1; w < 4; ++w) m += sred[w];
        sred[0] = m;
    }
    __syncthreads();
    float r = sred[0];
    __syncthreads();
    return r;
}

// A2 = Uh * softmax_rows(L fp16) -> fp16 (x1024) + rowsum(A2); one block per row
__global__ __launch_bounds__(256)
void softmax_mul_f16s(const unsigned short* __restrict__ Lrow,
                      const unsigned short* __restrict__ Uh,
                      unsigned short* __restrict__ hi, float* __restrict__ rowsum, int Ncols)
{
    __shared__ float srow[8192];
    __shared__ float sred[8];
    const int t = threadIdx.x;
    const size_t base = (size_t)blockIdx.x * Ncols;

    float lmax = -3.402823466e38f;
    for (int c = t * 4; c < Ncols; c += 1024) {
        us4 lv = *(const us4*)(Lrow + base + c);
        float4 v;
        v.x = h2f(lv.x); v.y = h2f(lv.y); v.z = h2f(lv.z); v.w = h2f(lv.w);
        *(float4*)&srow[c] = v;
        lmax = fmaxf(lmax, fmaxf(fmaxf(v.x, v.y), fmaxf(v.z, v.w)));
    }
    const float rmax = blockReduceMax(lmax, sred);

    float lsum = 0.f;
    for (int c = t * 4; c < Ncols; c += 1024) {
        float4 v = *(float4*)&srow[c];
        v.x = __expf(v.x - rmax);
        v.y = __expf(v.y - rmax);
        v.z = __expf(v.z - rmax);
        v.w = __expf(v.w - rmax);
        *(float4*)&srow[c] = v;
        lsum += v.x + v.y + v.z + v.w;
    }
    const float rsum = blockReduceSum(lsum, sred);
    const float inv = 1.f / rsum;

    float a2sum = 0.f;
    for (int c = t * 4; c < Ncols; c += 1024) {
        float4 e = *(float4*)&srow[c];
        us4 u = *(const us4*)(Uh + base + c);
        float a0 = h2f(u.x) * e.x * inv, a1 = h2f(u.y) * e.y * inv;
        float a2 = h2f(u.z) * e.z * inv, a3 = h2f(u.w) * e.w * inv;
        a2sum += a0 + a1 + a2 + a3;
        us4 h;
        h.x = f2h(a0 * 1024.f);
        h.y = f2h(a1 * 1024.f);
        h.z = f2h(a2 * 1024.f);
        h.w = f2h(a3 * 1024.f);
        *(us4*)(hi + base + c) = h;
    }
    const float rssum = blockReduceSum(a2sum, sred);
    if (t == 0) rowsum[blockIdx.x] = rssum;
}

// ---------------------------------------------------------------- old engine (fallback)
template<int FM, int WM, int WN, int EPI>
__global__ __launch_bounds__(WM * WN * 64)
void gemm_mfma(const unsigned short* __restrict__ Ahi,
               const unsigned short* __restrict__ Bh, float* __restrict__ Cf,
               unsigned short* __restrict__ Ch,
               int M, int Ncol, int Kdim)
{
    constexpr int NWAVES = WM * WN;
    constexpr int BM = WM * FM * 16;
    constexpr int BN = WN * 64;
    constexpr int ABYTES = BM * 64;
    constexpr int BBYTES = BN * 64;
    constexpr int LDSB = ABYTES + BBYTES;
    constexpr int CPW = LDSB / 1024 / NWAVES;

    __shared__ __align__(1024) char lds[2][LDSB];

    const int t = threadIdx.x;
    const int w = t >> 6, lane = t & 63;

    const int gx = gridDim.x;
    const int nwg = gx * gridDim.y;
    const int lid = blockIdx.y * gx + blockIdx.x;
    const int tl = (lid & 7) * (nwg >> 3) + (lid >> 3);
    const int m0 = (tl / gx) * BM, n0 = (tl % gx) * BN;

    const int kseg = Kdim / gridDim.z;
    const int kbeg = blockIdx.z * kseg;
    const int ksteps = kseg >> 5;
    const size_t zoff = (size_t)blockIdx.z * ((size_t)M * Ncol);

    const int wr = w / WN, wc = w % WN;
    const int l15 = lane & 15, kq = lane >> 4;

    const char* gsrc[CPW];
    int lofs[CPW];
#pragma unroll
    for (int c = 0; c < CPW; ++c) {
        const int boff = (w * CPW + c) * 1024;
        lofs[c] = boff;
        const int poff = swz(boff + lane * 16);
        const unsigned short* mat;
        int moff, rbase;
        if (poff < ABYTES) { mat = Ahi; moff = poff;          rbase = m0; }
        else               { mat = Bh;  moff = poff - ABYTES; rbase = n0; }
        gsrc[c] = (const char*)(mat + (size_t)(rbase + (moff >> 6)) * Kdim + kbeg) + (moff & 63);
    }

    int aoffS[FM], boffS[4];
#pragma unroll
    for (int m = 0; m < FM; ++m)
        aoffS[m] = swz((wr * (FM * 16) + m * 16 + l15) * 64 + kq * 16);
#pragma unroll
    for (int n = 0; n < 4; ++n)
        boffS[n] = swz(ABYTES + (wc * 64 + n * 16 + l15) * 64 + kq * 16);

    f32x4 acc[FM][4];
#pragma unroll
    for (int m = 0; m < FM; ++m)
#pragma unroll
        for (int n = 0; n < 4; ++n)
            acc[m][n] = (f32x4)(0.f);

    auto stage = [&](int buf) {
#pragma unroll
        for (int c = 0; c < CPW; ++c) {
            gload_lds16(gsrc[c], &lds[buf][lofs[c]]);
            gsrc[c] += 64;
        }
    };

    stage(0);
    __syncthreads();

    int cur = 0;
    for (int ks = 0; ks < ksteps; ++ks) {
        if (ks + 1 < ksteps) stage(cur ^ 1);

        const char* Lb = lds[cur];
        bf16x8 ah[FM], bb[4];
#pragma unroll
        for (int m = 0; m < FM; ++m)
            ah[m] = *(const bf16x8*)(Lb + aoffS[m]);
#pragma unroll
        for (int n = 0; n < 4; ++n)
            bb[n] = *(const bf16x8*)(Lb + boffS[n]);

        __builtin_amdgcn_s_setprio(1);
#pragma unroll
        for (int n = 0; n < 4; ++n)
#pragma unroll
            for (int m = 0; m < FM; ++m)
                acc[m][n] = mfma16(ah[m], bb[n], acc[m][n]);
        __builtin_amdgcn_s_setprio(0);

        __syncthreads();
        cur ^= 1;
    }

#pragma unroll
    for (int m = 0; m < FM; ++m) {
        const int rowb = m0 + wr * (FM * 16) + m * 16 + kq * 4;
#pragma unroll
        for (int n = 0; n < 4; ++n) {
            const int col = n0 + wc * 64 + n * 16 + l15;
#pragma unroll
            for (int r = 0; r < 4; ++r) {
                float v = acc[m][n][r];
                const size_t idx = (size_t)(rowb + r) * Ncol + col;
                if constexpr (EPI == 0) {
                    Cf[zoff + idx] = v;
                } else if constexpr (EPI == 2) {
                    Cf[idx] = 1.f / (1.f + __expf(-v));
                } else {
                    Ch[idx] = f2h(v);
                }
            }
        }
    }
}

// ---------------------------------------------------------------- fp32 fallback
template<int EPI, bool TB>
__global__ __launch_bounds__(256)
void gemm_f32(const float* __restrict__ A, const float* __restrict__ B,
              const float* __restrict__ bias, float* __restrict__ C,
              int M, int Ncol, int Kdim)
{
    constexpr int FBM = 128, FBN = 128, FBK = 8;
    __shared__ float As[FBK][FBM];
    __shared__ float Bs[FBK][FBN];
    const int t  = threadIdx.x;
    const int tx = t & 15, ty = t >> 4;
    const int m0 = blockIdx.y * FBM, n0 = blockIdx.x * FBN;

    const int arow  = t >> 1;
    const int acol4 = (t & 1) * 4;
    const int brow  = t >> 5;
    const int bcol4 = (t & 31) * 4;

    float acc[8][8];
#pragma unroll
    for (int i = 0; i < 8; ++i)
#pragma unroll
        for (int j = 0; j < 8; ++j) acc[i][j] = 0.f;

    const float* Aptr = A + (size_t)(m0 + arow) * Kdim + acol4;
    const float* Bptr;
    if (TB) Bptr = B + (size_t)(n0 + arow) * Kdim + acol4;
    else    Bptr = B + (size_t)brow * Ncol + n0 + bcol4;

    float4 av = *(const float4*)(Aptr);
    float4 bv = *(const float4*)(Bptr);

    for (int k0 = 0; k0 < Kdim; k0 += FBK) {
        As[acol4 + 0][arow] = av.x;
        As[acol4 + 1][arow] = av.y;
        As[acol4 + 2][arow] = av.z;
        As[acol4 + 3][arow] = av.w;
        if (TB) {
            Bs[acol4 + 0][arow] = bv.x;
            Bs[acol4 + 1][arow] = bv.y;
            Bs[acol4 + 2][arow] = bv.z;
            Bs[acol4 + 3][arow] = bv.w;
        } else {
            *(float4*)&Bs[brow][bcol4] = bv;
        }
        __syncthreads();

        if (k0 + FBK < Kdim) {
            av = *(const float4*)(Aptr + (k0 + FBK));
            if (TB) bv = *(const float4*)(Bptr + (k0 + FBK));
            else    bv = *(const float4*)(Bptr + (size_t)(k0 + FBK) * Ncol);
        }

#pragma unroll
        for (int kk = 0; kk < FBK; ++kk) {
            float a[8], b[8];
            *(float4*)&a[0] = *(const float4*)&As[kk][ty * 4];
            *(float4*)&a[4] = *(const float4*)&As[kk][64 + ty * 4];
            *(float4*)&b[0] = *(const float4*)&Bs[kk][tx * 4];
            *(float4*)&b[4] = *(const float4*)&Bs[kk][64 + tx * 4];
#pragma unroll
            for (int i = 0; i < 8; ++i)
#pragma unroll
                for (int j = 0; j < 8; ++j)
                    acc[i][j] = fmaf(a[i], b[j], acc[i][j]);
        }
        __syncthreads();
    }

#pragma unroll
    for (int ib = 0; ib < 2; ++ib) {
#pragma unroll
        for (int ii = 0; ii < 4; ++ii) {
            const int i = ib * 4 + ii;
            const size_t row = (size_t)(m0 + ib * 64 + ty * 4 + ii);
            float* crow = C + row * (size_t)Ncol;
#pragma unroll
            for (int jb = 0; jb < 2; ++jb) {
                const int col0 = n0 + jb * 64 + tx * 4;
                float4 v;
                v.x = acc[i][jb * 4 + 0];
                v.y = acc[i][jb * 4 + 1];
                v.z = acc[i][jb * 4 + 2];
                v.w = acc[i][jb * 4 + 3];
                if (EPI == 1) {
                    v.x = tanhf(v.x + bias[col0 + 0]);
                    v.y = tanhf(v.y + bias[col0 + 1]);
                    v.z = tanhf(v.z + bias[col0 + 2]);
                    v.w = tanhf(v.w + bias[col0 + 3]);
                } else if (EPI == 2) {
                    v.x = 1.f / (1.f + __expf(-v.x));
                    v.y = 1.f / (1.f + __expf(-v.y));
                    v.z = 1.f / (1.f + __expf(-v.z));
                    v.w = 1.f / (1.f + __expf(-v.w));
                }
                *(float4*)(crow + col0) = v;
            }
        }
    }
}

__global__ __launch_bounds__(256)
void softmax_mul_f32(float* buf, const float* __restrict__ U, int Ncols)
{
    __shared__ float srow[8192];
    __shared__ float sred[8];
    const int t = threadIdx.x;
    const size_t base = (size_t)blockIdx.x * Ncols;

    float lmax = -3.402823466e38f;
    for (int c = t * 4; c < Ncols; c += 1024) {
        float4 v = *(const float4*)(buf + base + c);
        *(float4*)&srow[c] = v;
        lmax = fmaxf(lmax, fmaxf(fmaxf(v.x, v.y), fmaxf(v.z, v.w)));
    }
    const float rmax = blockReduceMax(lmax, sred);

    float lsum = 0.f;
    for (int c = t * 4; c < Ncols; c += 1024) {
        float4 v = *(float4*)&srow[c];
        v.x = __expf(v.x - rmax);
        v.y = __expf(v.y - rmax);
        v.z = __expf(v.z - rmax);
        v.w = __expf(v.w - rmax);
        *(float4*)&srow[c] = v;
        lsum += v.x + v.y + v.z + v.w;
    }
    const float rsum = blockReduceSum(lsum, sred);
    const float inv = 1.f / rsum;

    for (int c = t * 4; c < Ncols; c += 1024) {
        float4 e = *(float4*)&srow[c];
        float4 u = *(const float4*)(U + base + c);
        float4 o;
        o.x = u.x * e.x * inv;
        o.y = u.y * e.y * inv;
        o.z = u.z * e.z * inv;
        o.w = u.w * e.w * inv;
        *(float4*)(buf + base + c) = o;
    }
}

__global__ __launch_bounds__(256)
void softmax_inplace_small(float* buf, int D)
{
    __shared__ float sred[8];
    const int t = threadIdx.x;
    const size_t base = (size_t)blockIdx.x * D;
    float2 v = *(float2*)(buf + base + t * 2);
    const float rmax = blockReduceMax(fmaxf(v.x, v.y), sred);
    const float e0 = __expf(v.x - rmax);
    const float e1 = __expf(v.y - rmax);
    const float rsum = blockReduceSum(e0 + e1, sred);
    const float inv = 1.f / rsum;
    float2 o;
    o.x = e0 * inv;
    o.y = e1 * inv;
    *(float2*)(buf + base + t * 2) = o;
}

// ---------------------------------------------------------------- launch
extern "C" void kernel_launch(void* const* d_in, const int* in_sizes, int n_in,
                              void* d_out, int out_size, void* d_ws, size_t ws_size,
                              hipStream_t stream)
{
    const float* U  = (const float*)d_in[0];
    const float* X  = (const float*)d_in[1];
    const float* H1 = (const float*)d_in[2];
    const float* W0 = (const float*)d_in[3];
    const float* W1 = (const float*)d_in[4];
    const float* Wa = (const float*)d_in[5];
    const float* ba = (const float*)d_in[6];
    const int D = in_sizes[6];
    const int N = (int)((long long)in_sizes[2] / D);
    const size_t NN = (size_t)N * N, ND = (size_t)N * D;

    float* Xp = (float*)d_out;          // [N,N] final; scratch for L (as fp16)
    float* Zp = Xp + NN;                // [N,D] final Z

    char* p = (char*)d_ws;
    auto alloc = [&](size_t bytes) { char* r = p; p += (bytes + 255) & ~(size_t)255; return r; };
    unsigned short* wa_h  = (unsigned short*)alloc(ND * 2);
    unsigned short* h1_h  = (unsigned short*)alloc(ND * 2);
    unsigned short* k_h   = (unsigned short*)alloc(ND * 2);
    unsigned short* w0t_h = (unsigned short*)alloc(ND * 2);
    unsigned short* vbt   = (unsigned short*)alloc(ND * 2);
    unsigned short* zt_h  = (unsigned short*)alloc(ND * 2);
    unsigned short* uz_h  = (unsigned short*)alloc(ND * 2);
    unsigned short* w1t_h = (unsigned short*)alloc(ND * 2);
    float*          xw0f  = (float*)alloc(ND * 4);
    float*          cvec  = (float*)alloc((size_t)D * 4);
    float*          rsum  = (float*)alloc((size_t)N * 4);
    float*          Pp    = (float*)alloc(ND * 4 * 4);        // splitK=4 partials
    unsigned short* Uh    = (unsigned short*)alloc(NN * 2);
    unsigned short* Xh    = (unsigned short*)alloc(NN * 2);
    const size_t need = (size_t)(p - (char*)d_ws);

    dim3 blk(256), blk512(512);

    if (N == 8192 && D == 512 && ws_size >= need) {
        constexpr int LDS8P = 131072;
        bool ok8p = true;
        ok8p &= hipFuncSetAttribute((const void*)gemm8p<0>,
                    hipFuncAttributeMaxDynamicSharedMemorySize, LDS8P) == hipSuccess;
        ok8p &= hipFuncSetAttribute((const void*)gemm8p<2>,
                    hipFuncAttributeMaxDynamicSharedMemorySize, LDS8P) == hipSuccess;
        ok8p &= hipFuncSetAttribute((const void*)gemm8p<3>,
                    hipFuncAttributeMaxDynamicSharedMemorySize, LDS8P) == hipSuccess;

        unsigned short* Lh = (unsigned short*)Xp;
        const dim3 gSlim8(D / 256, N / 256, 4);    // (2,32,4) splitK slims
        const dim3 gBig8(N / 256, N / 256);        // (32,32) bigs
        const dim3 gSlimK(D / 128, N / 128, 4);
        const dim3 gBig(N / 256, N / 128);
        const dim3 gT(D / 32, N / 32);
        const dim3 gTw1(N / 32, D / 32);
        const dim3 gRed((unsigned)(ND / 1024));    // elementwise reduces
        const int cgrid = 4096;
        unsigned short* nullw = nullptr;
        const float* nullf = nullptr;

        auto slimGemm = [&](const unsigned short* A_, const unsigned short* B_, float* C_) {
            if (ok8p)
                hipLaunchKernelGGL((gemm8p<0>), gSlim8, blk512, LDS8P, stream,
                                   A_, B_, C_, nullw, N, D, N);
            else
                hipLaunchKernelGGL((gemm_mfma<4, 2, 2, 0>), gSlimK, blk, 0, stream,
                                   A_, B_, C_, nullw, N, D, N);
        };

        // U, Wa -> fp16
        hipLaunchKernelGGL(convert_f16, dim3(cgrid), blk, 0, stream, U, Uh, NN);
        hipLaunchKernelGGL(convert_f16, dim3(1024), blk, 0, stream, Wa, wa_h, ND);
        // K = U @ Wa^T (splitK) -> reduce w/ tanh+bias -> k fp16
        slimGemm(Uh, wa_h, Pp);
        hipLaunchKernelGGL((reduce_splitk<0>), gRed, blk, 0, stream,
                           Pp, ND, ba, D, (float*)nullptr, k_h);
        hipLaunchKernelGGL(convert_f16, dim3(1024), blk, 0, stream, H1, h1_h, ND);
        // L = K @ H1^T -> fp16 Lh
        if (ok8p)
            hipLaunchKernelGGL((gemm8p<3>), gBig8, blk512, LDS8P, stream,
                               k_h, h1_h, (float*)nullptr, Lh, N, N, D);
        else
            hipLaunchKernelGGL((gemm_mfma<4, 2, 4, 3>), gBig, blk512, 0, stream,
                               k_h, h1_h, (float*)nullptr, Lh, N, N, D);
        // X -> fp16
        hipLaunchKernelGGL(convert_f16, dim3(cgrid), blk, 0, stream, X, Xh, NN);
        hipLaunchKernelGGL((transpose_cvt<false>), gT, blk, 0, stream, W0, w0t_h, nullf, N, D);
        // XW0 = X @ W0 (splitK) -> reduce -> xw0f
        slimGemm(Xh, w0t_h, Pp);
        hipLaunchKernelGGL((reduce_splitk<1>), gRed, blk, 0, stream,
                           Pp, ND, nullf, D, xw0f, nullw);
        // column means of XW0
        hipMemsetAsync(cvec, 0, (size_t)D * 4, stream);
        hipLaunchKernelGGL(colsum512, dim3(N / 16), blk, 0, stream, xw0f, cvec, N);
        hipLaunchKernelGGL(scale_vec, dim3(1), dim3(512), 0, stream, cvec, 1.0f / (float)N, D);
        // V = (XW0 - c)^T -> fp16 [D][N]
        hipLaunchKernelGGL((transpose_cvt<true>), gT, blk, 0, stream, xw0f, vbt, cvec, N, D);
        // A2s = 1024 * Uh * softmax(L fp16) -> fp16 + rowsum
        hipLaunchKernelGGL(softmax_mul_f16s, dim3(N), blk, 0, stream, Lh, Uh, Xh, rsum, N);
        // T = A2s @ V (splitK); fused reduce+affine+softmax(reg)+transpose
        slimGemm(Xh, vbt, Pp);
        hipLaunchKernelGGL(reduce_softmax4_t, dim3(N / 4), blk, 0, stream,
                           Pp, ND, rsum, cvec, 1.0f / 1024.f, Zp, zt_h, N);
        // UZ = U @ Z (splitK) -> reduce -> uz fp16
        slimGemm(Uh, zt_h, Pp);
        hipLaunchKernelGGL((reduce_splitk<3>), gRed, blk, 0, stream,
                           Pp, ND, nullf, D, (float*)nullptr, uz_h);
        hipLaunchKernelGGL((transpose_cvt<false>), gTw1, blk, 0, stream, W1, w1t_h, nullf, D, N);
        // Xp = sigmoid(UZ @ W1)
        if (ok8p)
            hipLaunchKernelGGL((gemm8p<2>), gBig8, blk512, LDS8P, stream,
                               uz_h, w1t_h, Xp, nullw, N, N, D);
        else
            hipLaunchKernelGGL((gemm_mfma<4, 2, 4, 2>), gBig, blk512, 0, stream,
                               uz_h, w1t_h, Xp, nullw, N, N, D);
    } else {
        // -------- fp32 fallback
        float* bufA = (float*)d_ws;
        dim3 gD(D / 128, N / 128);
        dim3 gN(N / 128, N / 128);
        hipLaunchKernelGGL((gemm_f32<1, true>),  gD, blk, 0, stream, U,    Wa, ba,      bufA, N, D, N);
        hipLaunchKernelGGL((gemm_f32<0, true>),  gN, blk, 0, stream, bufA, H1, nullptr, Xp,   N, N, D);
        hipLaunchKernelGGL(softmax_mul_f32, dim3(N), blk, 0, stream, Xp, U, N);
        hipLaunchKernelGGL((gemm_f32<0, false>), gD, blk, 0, stream, X,    W0, nullptr, bufA, N, D, N);
        hipLaunchKernelGGL((gemm_f32<0, false>), gD, blk, 0, stream, Xp,   bufA, nullptr, Zp, N, D, N);
        hipLaunchKernelGGL(softmax_inplace_small, dim3(N), blk, 0, stream, Zp, D);
        hipLaunchKernelGGL((gemm_f32<0, false>), gD, blk, 0, stream, U,    Zp, nullptr, bufA, N, D, N);
        hipLaunchKernelGGL((gemm_f32<2, false>), gN, blk, 0, stream, bufA, W1, nullptr, Xp,  N, N, D);
    }
}

// Round 12
// 892.829 us; speedup vs baseline: 1.0974x; 1.0225x over previous
//
#include <hip/hip_runtime.h>
#include <math.h>

// GCNNet: N=8192, D=512. Round-11 base (913 us) + traffic cuts:
//   - K and UZ splitK partials stored fp16 (safe ranges); XW0/T stay f32
//   - scale_vec folded into transpose_cvt / reduce_softmax4_t (exact)
//   - Wa+H1 converts merged into one launch
// GEMM engine: 256x256-tile 8-wave 8-phase schedule (K-half regions, counted
// vmcnt, raw s_barrier, 128KB dynamic LDS); round-8 engine as fallback.

typedef __attribute__((ext_vector_type(8))) short bf16x8;     // raw 16B container
typedef __attribute__((ext_vector_type(8))) _Float16 f16x8;
typedef __attribute__((ext_vector_type(4))) float f32x4;
typedef __attribute__((ext_vector_type(4))) unsigned short us4;

__device__ __forceinline__ unsigned short f2h(float x) {
    _Float16 h = (_Float16)x;
    return __builtin_bit_cast(unsigned short, h);
}
__device__ __forceinline__ float h2f(unsigned short u) {
    return (float)__builtin_bit_cast(_Float16, u);
}

__device__ __forceinline__ void gload_lds16(const char* g, char* l) {
    __builtin_amdgcn_global_load_lds(
        (const __attribute__((address_space(1))) unsigned int*)g,
        (__attribute__((address_space(3))) unsigned int*)l, 16, 0, 0);
}

// XOR bank swizzles (involutions, preserve 16B alignment)
__device__ __forceinline__ int swz(int o) {
    return o ^ (((o >> 7) & 7) << 4);
}
__device__ __forceinline__ int swzk(int o) {
    return o ^ (((o >> 7) & 3) << 4);
}

__device__ __forceinline__ f32x4 mfma16(bf16x8 a, bf16x8 b, f32x4 c) {
    return __builtin_amdgcn_mfma_f32_16x16x32_f16(
        __builtin_bit_cast(f16x8, a), __builtin_bit_cast(f16x8, b), c, 0, 0, 0);
}

// ================================================================ 8-phase GEMM
// A [M,K] fp16 row-major, B [Ncol,K] fp16 row-major. 256x256 tile, 8 waves.
// BK=64 as two K-halves; regions A_k0,A_k1,B_k0,B_k1 (16KB each); dbuf 128KB.
// splitK via gridDim.z. EPI: 0 f32 (+zoff), 2 sigmoid f32, 3 fp16 (+zoff).
template<int EPI>
__global__ __launch_bounds__(512, 1)
void gemm8p(const unsigned short* __restrict__ A, const unsigned short* __restrict__ B,
            float* __restrict__ Cf, unsigned short* __restrict__ Ch,
            int M, int Ncol, int Kdim)
{
    extern __shared__ char lds[];            // 131072 bytes
    constexpr int RSZ = 16384;               // region bytes

    const int tid = threadIdx.x;
    const int w = tid >> 6, lane = tid & 63;
    const int wr = w >> 2, wc = w & 3;       // 2 x 4 wave grid
    const int l15 = lane & 15, kq = lane >> 4;

    const int gx = gridDim.x;
    const int nwg = gx * gridDim.y;
    const int lid = blockIdx.y * gx + blockIdx.x;
    const int tl = (lid & 7) * (nwg >> 3) + (lid >> 3);
    const int m0 = (tl / gx) * 256, n0 = (tl % gx) * 256;

    const int kseg = Kdim / gridDim.z;
    const int kbeg = blockIdx.z * kseg;
    const int T = kseg >> 6;                 // BK = 64
    const size_t zoff = (size_t)blockIdx.z * ((size_t)M * Ncol);

    const int Kb = Kdim * 2;
    const char* gp[4][2];
    {
        const char* Ab = (const char*)A + (size_t)m0 * Kb + (size_t)kbeg * 2;
        const char* Bb = (const char*)B + (size_t)n0 * Kb + (size_t)kbeg * 2;
#pragma unroll
        for (int r = 0; r < 4; ++r) {
            const char* base = (r < 2) ? Ab : Bb;
            const int khalf = r & 1;
#pragma unroll
            for (int j = 0; j < 2; ++j) {
                const int moff = swzk((w * 2 + j) * 1024 + lane * 16);
                gp[r][j] = base + (size_t)(moff >> 6) * Kb + khalf * 64 + (moff & 63);
            }
        }
    }

    auto stage = [&](int r, int tile) {
        char* dst = lds + (tile & 1) * 65536 + r * RSZ + w * 2048;
        gload_lds16(gp[r][0] + (size_t)tile * 128, dst);
        gload_lds16(gp[r][1] + (size_t)tile * 128, dst + 1024);
    };

    int aoff[8], boff[4];
#pragma unroll
    for (int mf = 0; mf < 8; ++mf)
        aoff[mf] = swzk((wr * 128 + mf * 16 + l15) * 64 + kq * 16);
#pragma unroll
    for (int n = 0; n < 4; ++n)
        boff[n] = swzk((wc * 64 + n * 16 + l15) * 64 + kq * 16);

    f32x4 acc[8][4];
#pragma unroll
    for (int m = 0; m < 8; ++m)
#pragma unroll
        for (int n = 0; n < 4; ++n)
            acc[m][n] = (f32x4)(0.f);

    stage(2, 0); stage(0, 0); stage(3, 0); stage(1, 0);
    stage(2, 1); stage(0, 1); stage(3, 1);
    asm volatile("s_waitcnt vmcnt(10)" ::: "memory");
    __builtin_amdgcn_s_barrier();

    for (int t = 0; t < T; ++t) {
        const char* Lb = lds + (t & 1) * 65536;
        bf16x8 bfr[4], afr[4];

        // phase 0: kk0, mf 0-3
#pragma unroll
        for (int n = 0; n < 4; ++n) bfr[n] = *(const bf16x8*)(Lb + 2 * RSZ + boff[n]);
#pragma unroll
        for (int m = 0; m < 4; ++m) afr[m] = *(const bf16x8*)(Lb + 0 * RSZ + aoff[m]);
        if (t + 1 < T) stage(1, t + 1);
        __builtin_amdgcn_s_barrier();
        __builtin_amdgcn_s_setprio(1);
#pragma unroll
        for (int n = 0; n < 4; ++n)
#pragma unroll
            for (int m = 0; m < 4; ++m)
                acc[m][n] = mfma16(afr[m], bfr[n], acc[m][n]);
        __builtin_amdgcn_s_setprio(0);
        __builtin_amdgcn_sched_barrier(0);
        __builtin_amdgcn_s_barrier();

        // phase 1: kk0, mf 4-7
#pragma unroll
        for (int m = 0; m < 4; ++m) afr[m] = *(const bf16x8*)(Lb + 0 * RSZ + aoff[4 + m]);
        if (t + 2 < T) stage(2, t + 2);
        __builtin_amdgcn_s_barrier();
        __builtin_amdgcn_s_setprio(1);
#pragma unroll
        for (int n = 0; n < 4; ++n)
#pragma unroll
            for (int m = 0; m < 4; ++m)
                acc[4 + m][n] = mfma16(afr[m], bfr[n], acc[4 + m][n]);
        __builtin_amdgcn_s_setprio(0);
        __builtin_amdgcn_sched_barrier(0);
        if (t < T - 2)       { asm volatile("s_waitcnt vmcnt(10)" ::: "memory"); }
        else if (t == T - 2) { asm volatile("s_waitcnt vmcnt(8)"  ::: "memory"); }
        else                 { asm volatile("s_waitcnt vmcnt(0)"  ::: "memory"); }
        __builtin_amdgcn_s_barrier();

        // phase 2: kk1, mf 0-3
#pragma unroll
        for (int n = 0; n < 4; ++n) bfr[n] = *(const bf16x8*)(Lb + 3 * RSZ + boff[n]);
#pragma unroll
        for (int m = 0; m < 4; ++m) afr[m] = *(const bf16x8*)(Lb + 1 * RSZ + aoff[m]);
        if (t + 2 < T) stage(0, t + 2);
        __builtin_amdgcn_s_barrier();
        __builtin_amdgcn_s_setprio(1);
#pragma unroll
        for (int n = 0; n < 4; ++n)
#pragma unroll
            for (int m = 0; m < 4; ++m)
                acc[m][n] = mfma16(afr[m], bfr[n], acc[m][n]);
        __builtin_amdgcn_s_setprio(0);
        __builtin_amdgcn_sched_barrier(0);
        __builtin_amdgcn_s_barrier();

        // phase 3: kk1, mf 4-7
#pragma unroll
        for (int m = 0; m < 4; ++m) afr[m] = *(const bf16x8*)(Lb + 1 * RSZ + aoff[4 + m]);
        if (t + 2 < T) stage(3, t + 2);
        __builtin_amdgcn_s_barrier();
        __builtin_amdgcn_s_setprio(1);
#pragma unroll
        for (int n = 0; n < 4; ++n)
#pragma unroll
            for (int m = 0; m < 4; ++m)
                acc[4 + m][n] = mfma16(afr[m], bfr[n], acc[4 + m][n]);
        __builtin_amdgcn_s_setprio(0);
        __builtin_amdgcn_sched_barrier(0);
        if (t + 1 < T) {
            if (t + 2 < T) { asm volatile("s_waitcnt vmcnt(10)" ::: "memory"); }
            else           { asm volatile("s_waitcnt vmcnt(4)"  ::: "memory"); }
        }
        __builtin_amdgcn_s_barrier();
    }

#pragma unroll
    for (int m = 0; m < 8; ++m) {
        const int rowb = m0 + wr * 128 + m * 16 + kq * 4;
#pragma unroll
        for (int n = 0; n < 4; ++n) {
            const int col = n0 + wc * 64 + n * 16 + l15;
#pragma unroll
            for (int r = 0; r < 4; ++r) {
                float v = acc[m][n][r];
                const size_t idx = (size_t)(rowb + r) * Ncol + col;
                if constexpr (EPI == 0) {
                    Cf[zoff + idx] = v;
                } else if constexpr (EPI == 2) {
                    Cf[idx] = 1.f / (1.f + __expf(-v));
                } else {
                    Ch[zoff + idx] = f2h(v);
                }
            }
        }
    }
}

// ---------------------------------------------------------------- converts
__global__ __launch_bounds__(256)
void convert_f16(const float* __restrict__ in, unsigned short* __restrict__ hi, size_t n)
{
    size_t i = ((size_t)blockIdx.x * blockDim.x + threadIdx.x) * 4;
    const size_t stride = (size_t)gridDim.x * blockDim.x * 4;
    for (; i < n; i += stride) {
        float4 v = *(const float4*)(in + i);
        us4 h;
        h.x = f2h(v.x); h.y = f2h(v.y); h.z = f2h(v.z); h.w = f2h(v.w);
        *(us4*)(hi + i) = h;
    }
}

// two arrays of n elems each in one launch (grid = 2*n/1024)
__global__ __launch_bounds__(256)
void convert2_f16(const float* __restrict__ a, unsigned short* __restrict__ ah,
                  const float* __restrict__ b, unsigned short* __restrict__ bh, size_t n)
{
    const unsigned half = gridDim.x >> 1;
    const bool second = blockIdx.x >= half;
    const float* src = second ? b : a;
    unsigned short* dst = second ? bh : ah;
    const unsigned bid = second ? blockIdx.x - half : blockIdx.x;
    const size_t i = ((size_t)bid * blockDim.x + threadIdx.x) * 4;
    if (i < n) {
        float4 v = *(const float4*)(src + i);
        us4 h;
        h.x = f2h(v.x); h.y = f2h(v.y); h.z = f2h(v.z); h.w = f2h(v.w);
        *(us4*)(dst + i) = h;
    }
}

// fp32 [R][C] -> fp16 [C][R]; optional v -= cvec[col]*csc
template<bool CSUB>
__global__ __launch_bounds__(256)
void transpose_cvt(const float* __restrict__ in, unsigned short* __restrict__ hi,
                   const float* __restrict__ cvec, float csc, int R, int C)
{
    __shared__ float tile[32][33];
    const int t = threadIdx.x, tx = t & 31, ty = t >> 5;
    const int c0 = blockIdx.x * 32, r0 = blockIdx.y * 32;
#pragma unroll
    for (int i = 0; i < 4; ++i)
        tile[ty + 8 * i][tx] = in[(size_t)(r0 + ty + 8 * i) * C + c0 + tx];
    __syncthreads();
#pragma unroll
    for (int i = 0; i < 4; ++i) {
        const int col = c0 + ty + 8 * i;
        float v = tile[tx][ty + 8 * i];
        if (CSUB) v -= cvec[col] * csc;
        hi[(size_t)col * R + r0 + tx] = f2h(v);
    }
}

// column sums of [Nrows x 512] fp32 (atomic partials; raw sums)
__global__ __launch_bounds__(256)
void colsum512(const float* __restrict__ in, float* __restrict__ c, int Nrows)
{
    const int t = threadIdx.x;
    const int r0 = blockIdx.x * 16;
    float s0 = 0.f, s1 = 0.f;
    for (int r = 0; r < 16; ++r) {
        const float* row = in + (size_t)(r0 + r) * 512;
        s0 += row[t];
        s1 += row[t + 256];
    }
    atomicAdd(&c[t], s0);
    atomicAdd(&c[t + 256], s1);
}

// ---------------------------------------------------------------- splitK reduces
// f32 partials. RED: 0 = tanh(s+ba[col]) -> fp16 ; 1 = f32 ; 3 = fp16
template<int RED>
__global__ __launch_bounds__(256)
void reduce_splitk(const float* __restrict__ P, size_t seg,
                   const float* __restrict__ ba, int Ncol,
                   float* __restrict__ outf, unsigned short* __restrict__ outh)
{
    const size_t i = ((size_t)blockIdx.x * blockDim.x + threadIdx.x) * 4;
    float4 a = *(const float4*)(P + i);
    float4 b = *(const float4*)(P + seg + i);
    float4 c = *(const float4*)(P + 2 * seg + i);
    float4 d = *(const float4*)(P + 3 * seg + i);
    float s0 = a.x + b.x + c.x + d.x;
    float s1 = a.y + b.y + c.y + d.y;
    float s2 = a.z + b.z + c.z + d.z;
    float s3 = a.w + b.w + c.w + d.w;

    if constexpr (RED == 0) {
        const int col = (int)(i % (size_t)Ncol);
        us4 h;
        h.x = f2h(tanhf(s0 + ba[col + 0]));
        h.y = f2h(tanhf(s1 + ba[col + 1]));
        h.z = f2h(tanhf(s2 + ba[col + 2]));
        h.w = f2h(tanhf(s3 + ba[col + 3]));
        *(us4*)(outh + i) = h;
    } else if constexpr (RED == 1) {
        float4 o; o.x = s0; o.y = s1; o.z = s2; o.w = s3;
        *(float4*)(outf + i) = o;
    } else {
        us4 h;
        h.x = f2h(s0); h.y = f2h(s1); h.z = f2h(s2); h.w = f2h(s3);
        *(us4*)(outh + i) = h;
    }
}

// fp16 partials (K / UZ slims — safe magnitudes). RED: 0 tanh+bias, 3 plain.
template<int RED>
__global__ __launch_bounds__(256)
void reduce_splitk_h(const unsigned short* __restrict__ P, size_t seg,
                     const float* __restrict__ ba, int Ncol,
                     unsigned short* __restrict__ outh)
{
    const size_t i = ((size_t)blockIdx.x * blockDim.x + threadIdx.x) * 4;
    us4 a = *(const us4*)(P + i);
    us4 b = *(const us4*)(P + seg + i);
    us4 c = *(const us4*)(P + 2 * seg + i);
    us4 d = *(const us4*)(P + 3 * seg + i);
    float s0 = h2f(a.x) + h2f(b.x) + h2f(c.x) + h2f(d.x);
    float s1 = h2f(a.y) + h2f(b.y) + h2f(c.y) + h2f(d.y);
    float s2 = h2f(a.z) + h2f(b.z) + h2f(c.z) + h2f(d.z);
    float s3 = h2f(a.w) + h2f(b.w) + h2f(c.w) + h2f(d.w);

    us4 h;
    if constexpr (RED == 0) {
        const int col = (int)(i % (size_t)Ncol);
        h.x = f2h(tanhf(s0 + ba[col + 0]));
        h.y = f2h(tanhf(s1 + ba[col + 1]));
        h.z = f2h(tanhf(s2 + ba[col + 2]));
        h.w = f2h(tanhf(s3 + ba[col + 3]));
    } else {
        h.x = f2h(s0); h.y = f2h(s1); h.z = f2h(s2); h.w = f2h(s3);
    }
    *(us4*)(outh + i) = h;
}

// Fused: T = sum(4 f32 splitK planes)*scale + rs[row]*invN*cv_raw[col], row
// softmax in REGISTERS (one wave per row), writes Zp f32 + transposed fp16.
// 4 rows/block -> 2048 blocks (parallelism preserved).
__global__ __launch_bounds__(256)
void reduce_softmax4_t(const float* __restrict__ P, size_t seg,
                       const float* __restrict__ rs, const float* __restrict__ cv,
                       float scale, float invN,
                       float* __restrict__ Zp, unsigned short* __restrict__ zt, int N)
{
    __shared__ float s[4][516];
    __shared__ float scv[512];
    const int t = threadIdx.x, lane = t & 63, w = t >> 6;
    const int r0 = blockIdx.x * 4;
    if (t < 128) *(float4*)&scv[t * 4] = *(const float4*)(cv + t * 4);
    __syncthreads();

    const int row = r0 + w;
    const float rr = rs[row] * invN;
    const size_t base = (size_t)row * 512 + lane * 8;

    float vals[8];
#pragma unroll
    for (int h = 0; h < 2; ++h) {
        float4 a = *(const float4*)(P + base + h * 4);
        float4 b = *(const float4*)(P + seg + base + h * 4);
        float4 c = *(const float4*)(P + 2 * seg + base + h * 4);
        float4 d = *(const float4*)(P + 3 * seg + base + h * 4);
        const int j = h * 4;
        vals[j + 0] = (a.x + b.x + c.x + d.x) * scale + rr * scv[lane * 8 + j + 0];
        vals[j + 1] = (a.y + b.y + c.y + d.y) * scale + rr * scv[lane * 8 + j + 1];
        vals[j + 2] = (a.z + b.z + c.z + d.z) * scale + rr * scv[lane * 8 + j + 2];
        vals[j + 3] = (a.w + b.w + c.w + d.w) * scale + rr * scv[lane * 8 + j + 3];
    }

    float m = -3.402823466e38f;
#pragma unroll
    for (int j = 0; j < 8; ++j) m = fmaxf(m, vals[j]);
#pragma unroll
    for (int o = 32; o > 0; o >>= 1) m = fmaxf(m, __shfl_xor(m, o));
    float sum = 0.f;
#pragma unroll
    for (int j = 0; j < 8; ++j) { vals[j] = __expf(vals[j] - m); sum += vals[j]; }
#pragma unroll
    for (int o = 32; o > 0; o >>= 1) sum += __shfl_xor(sum, o);
    const float inv = 1.f / sum;

    float4 o1, o2;
    o1.x = vals[0] * inv; o1.y = vals[1] * inv; o1.z = vals[2] * inv; o1.w = vals[3] * inv;
    o2.x = vals[4] * inv; o2.y = vals[5] * inv; o2.z = vals[6] * inv; o2.w = vals[7] * inv;
    *(float4*)(Zp + base) = o1;
    *(float4*)(Zp + base + 4) = o2;
    *(float4*)&s[w][lane * 8] = o1;
    *(float4*)&s[w][lane * 8 + 4] = o2;
    __syncthreads();

#pragma unroll
    for (int cc = 0; cc < 2; ++cc) {
        const int col = t * 2 + cc;
        us4 h;
        h.x = f2h(s[0][col]);
        h.y = f2h(s[1][col]);
        h.z = f2h(s[2][col]);
        h.w = f2h(s[3][col]);
        *(us4*)(zt + (size_t)col * N + r0) = h;
    }
}

// ---------------------------------------------------------------- reductions
__device__ inline float blockReduceMax(float v, float* sred)
{
    for (int o = 32; o > 0; o >>= 1) v = fmaxf(v, __shfl_down(v, o));
    const int lane = threadIdx.x & 63, wid = threadIdx.x >> 6;
    if (lane == 0) sred[wid] = v;
    __syncthreads();
    if (threadIdx.x == 0) {
        float m = sred[0];
        for (int w = 1; w < 4; ++w) m = fmaxf(m, sred[w]);
        sred[0] = m;
    }
    __syncthreads();
    float r = sred[0];
    __syncthreads();
    return r;
}

__device__ inline float blockReduceSum(float v, float* sred)
{
    for (int o = 32; o > 0; o >>= 1) v += __shfl_down(v, o);
    const int lane = threadIdx.x & 63, wid = threadIdx.x >> 6;
    if (lane == 0) sred[wid] = v;
    __syncthreads();
    if (threadIdx.x == 0) {
        float m = sred[0];
        for (int w = 1; w < 4; ++w) m += sred[w];
        sred[0] = m;
    }
    __syncthreads();
    float r = sred[0];
    __syncthreads();
    return r;
}

// A2 = Uh * softmax_rows(L fp16) -> fp16 (x1024) + rowsum(A2); one block per row
__global__ __launch_bounds__(256)
void softmax_mul_f16s(const unsigned short* __restrict__ Lrow,
                      const unsigned short* __restrict__ Uh,
                      unsigned short* __restrict__ hi, float* __restrict__ rowsum, int Ncols)
{
    __shared__ float srow[8192];
    __shared__ float sred[8];
    const int t = threadIdx.x;
    const size_t base = (size_t)blockIdx.x * Ncols;

    float lmax = -3.402823466e38f;
    for (int c = t * 4; c < Ncols; c += 1024) {
        us4 lv = *(const us4*)(Lrow + base + c);
        float4 v;
        v.x = h2f(lv.x); v.y = h2f(lv.y); v.z = h2f(lv.z); v.w = h2f(lv.w);
        *(float4*)&srow[c] = v;
        lmax = fmaxf(lmax, fmaxf(fmaxf(v.x, v.y), fmaxf(v.z, v.w)));
    }
    const float rmax = blockReduceMax(lmax, sred);

    float lsum = 0.f;
    for (int c = t * 4; c < Ncols; c += 1024) {
        float4 v = *(float4*)&srow[c];
        v.x = __expf(v.x - rmax);
        v.y = __expf(v.y - rmax);
        v.z = __expf(v.z - rmax);
        v.w = __expf(v.w - rmax);
        *(float4*)&srow[c] = v;
        lsum += v.x + v.y + v.z + v.w;
    }
    const float rsum = blockReduceSum(lsum, sred);
    const float inv = 1.f / rsum;

    float a2sum = 0.f;
    for (int c = t * 4; c < Ncols; c += 1024) {
        float4 e = *(float4*)&srow[c];
        us4 u = *(const us4*)(Uh + base + c);
        float a0 = h2f(u.x) * e.x * inv, a1 = h2f(u.y) * e.y * inv;
        float a2 = h2f(u.z) * e.z * inv, a3 = h2f(u.w) * e.w * inv;
        a2sum += a0 + a1 + a2 + a3;
        us4 h;
        h.x = f2h(a0 * 1024.f);
        h.y = f2h(a1 * 1024.f);
        h.z = f2h(a2 * 1024.f);
        h.w = f2h(a3 * 1024.f);
        *(us4*)(hi + base + c) = h;
    }
    const float rssum = blockReduceSum(a2sum, sred);
    if (t == 0) rowsum[blockIdx.x] = rssum;
}

// ---------------------------------------------------------------- old engine (fallback)
template<int FM, int WM, int WN, int EPI>
__global__ __launch_bounds__(WM * WN * 64)
void gemm_mfma(const unsigned short* __restrict__ Ahi,
               const unsigned short* __restrict__ Bh, float* __restrict__ Cf,
               unsigned short* __restrict__ Ch,
               int M, int Ncol, int Kdim)
{
    constexpr int NWAVES = WM * WN;
    constexpr int BM = WM * FM * 16;
    constexpr int BN = WN * 64;
    constexpr int ABYTES = BM * 64;
    constexpr int BBYTES = BN * 64;
    constexpr int LDSB = ABYTES + BBYTES;
    constexpr int CPW = LDSB / 1024 / NWAVES;

    __shared__ __align__(1024) char lds[2][LDSB];

    const int t = threadIdx.x;
    const int w = t >> 6, lane = t & 63;

    const int gx = gridDim.x;
    const int nwg = gx * gridDim.y;
    const int lid = blockIdx.y * gx + blockIdx.x;
    const int tl = (lid & 7) * (nwg >> 3) + (lid >> 3);
    const int m0 = (tl / gx) * BM, n0 = (tl % gx) * BN;

    const int kseg = Kdim / gridDim.z;
    const int kbeg = blockIdx.z * kseg;
    const int ksteps = kseg >> 5;
    const size_t zoff = (size_t)blockIdx.z * ((size_t)M * Ncol);

    const int wr = w / WN, wc = w % WN;
    const int l15 = lane & 15, kq = lane >> 4;

    const char* gsrc[CPW];
    int lofs[CPW];
#pragma unroll
    for (int c = 0; c < CPW; ++c) {
        const int boff = (w * CPW + c) * 1024;
        lofs[c] = boff;
        const int poff = swz(boff + lane * 16);
        const unsigned short* mat;
        int moff, rbase;
        if (poff < ABYTES) { mat = Ahi; moff = poff;          rbase = m0; }
        else               { mat = Bh;  moff = poff - ABYTES; rbase = n0; }
        gsrc[c] = (const char*)(mat + (size_t)(rbase + (moff >> 6)) * Kdim + kbeg) + (moff & 63);
    }

    int aoffS[FM], boffS[4];
#pragma unroll
    for (int m = 0; m < FM; ++m)
        aoffS[m] = swz((wr * (FM * 16) + m * 16 + l15) * 64 + kq * 16);
#pragma unroll
    for (int n = 0; n < 4; ++n)
        boffS[n] = swz(ABYTES + (wc * 64 + n * 16 + l15) * 64 + kq * 16);

    f32x4 acc[FM][4];
#pragma unroll
    for (int m = 0; m < FM; ++m)
#pragma unroll
        for (int n = 0; n < 4; ++n)
            acc[m][n] = (f32x4)(0.f);

    auto stage = [&](int buf) {
#pragma unroll
        for (int c = 0; c < CPW; ++c) {
            gload_lds16(gsrc[c], &lds[buf][lofs[c]]);
            gsrc[c] += 64;
        }
    };

    stage(0);
    __syncthreads();

    int cur = 0;
    for (int ks = 0; ks < ksteps; ++ks) {
        if (ks + 1 < ksteps) stage(cur ^ 1);

        const char* Lb = lds[cur];
        bf16x8 ah[FM], bb[4];
#pragma unroll
        for (int m = 0; m < FM; ++m)
            ah[m] = *(const bf16x8*)(Lb + aoffS[m]);
#pragma unroll
        for (int n = 0; n < 4; ++n)
            bb[n] = *(const bf16x8*)(Lb + boffS[n]);

        __builtin_amdgcn_s_setprio(1);
#pragma unroll
        for (int n = 0; n < 4; ++n)
#pragma unroll
            for (int m = 0; m < FM; ++m)
                acc[m][n] = mfma16(ah[m], bb[n], acc[m][n]);
        __builtin_amdgcn_s_setprio(0);

        __syncthreads();
        cur ^= 1;
    }

#pragma unroll
    for (int m = 0; m < FM; ++m) {
        const int rowb = m0 + wr * (FM * 16) + m * 16 + kq * 4;
#pragma unroll
        for (int n = 0; n < 4; ++n) {
            const int col = n0 + wc * 64 + n * 16 + l15;
#pragma unroll
            for (int r = 0; r < 4; ++r) {
                float v = acc[m][n][r];
                const size_t idx = (size_t)(rowb + r) * Ncol + col;
                if constexpr (EPI == 0) {
                    Cf[zoff + idx] = v;
                } else if constexpr (EPI == 2) {
                    Cf[idx] = 1.f / (1.f + __expf(-v));
                } else {
                    Ch[idx] = f2h(v);
                }
            }
        }
    }
}

// ---------------------------------------------------------------- fp32 fallback
template<int EPI, bool TB>
__global__ __launch_bounds__(256)
void gemm_f32(const float* __restrict__ A, const float* __restrict__ B,
              const float* __restrict__ bias, float* __restrict__ C,
              int M, int Ncol, int Kdim)
{
    constexpr int FBM = 128, FBN = 128, FBK = 8;
    __shared__ float As[FBK][FBM];
    __shared__ float Bs[FBK][FBN];
    const int t  = threadIdx.x;
    const int tx = t & 15, ty = t >> 4;
    const int m0 = blockIdx.y * FBM, n0 = blockIdx.x * FBN;

    const int arow  = t >> 1;
    const int acol4 = (t & 1) * 4;
    const int brow  = t >> 5;
    const int bcol4 = (t & 31) * 4;

    float acc[8][8];
#pragma unroll
    for (int i = 0; i < 8; ++i)
#pragma unroll
        for (int j = 0; j < 8; ++j) acc[i][j] = 0.f;

    const float* Aptr = A + (size_t)(m0 + arow) * Kdim + acol4;
    const float* Bptr;
    if (TB) Bptr = B + (size_t)(n0 + arow) * Kdim + acol4;
    else    Bptr = B + (size_t)brow * Ncol + n0 + bcol4;

    float4 av = *(const float4*)(Aptr);
    float4 bv = *(const float4*)(Bptr);

    for (int k0 = 0; k0 < Kdim; k0 += FBK) {
        As[acol4 + 0][arow] = av.x;
        As[acol4 + 1][arow] = av.y;
        As[acol4 + 2][arow] = av.z;
        As[acol4 + 3][arow] = av.w;
        if (TB) {
            Bs[acol4 + 0][arow] = bv.x;
            Bs[acol4 + 1][arow] = bv.y;
            Bs[acol4 + 2][arow] = bv.z;
            Bs[acol4 + 3][arow] = bv.w;
        } else {
            *(float4*)&Bs[brow][bcol4] = bv;
        }
        __syncthreads();

        if (k0 + FBK < Kdim) {
            av = *(const float4*)(Aptr + (k0 + FBK));
            if (TB) bv = *(const float4*)(Bptr + (k0 + FBK));
            else    bv = *(const float4*)(Bptr + (size_t)(k0 + FBK) * Ncol);
        }

#pragma unroll
        for (int kk = 0; kk < FBK; ++kk) {
            float a[8], b[8];
            *(float4*)&a[0] = *(const float4*)&As[kk][ty * 4];
            *(float4*)&a[4] = *(const float4*)&As[kk][64 + ty * 4];
            *(float4*)&b[0] = *(const float4*)&Bs[kk][tx * 4];
            *(float4*)&b[4] = *(const float4*)&Bs[kk][64 + tx * 4];
#pragma unroll
            for (int i = 0; i < 8; ++i)
#pragma unroll
                for (int j = 0; j < 8; ++j)
                    acc[i][j] = fmaf(a[i], b[j], acc[i][j]);
        }
        __syncthreads();
    }

#pragma unroll
    for (int ib = 0; ib < 2; ++ib) {
#pragma unroll
        for (int ii = 0; ii < 4; ++ii) {
            const int i = ib * 4 + ii;
            const size_t row = (size_t)(m0 + ib * 64 + ty * 4 + ii);
            float* crow = C + row * (size_t)Ncol;
#pragma unroll
            for (int jb = 0; jb < 2; ++jb) {
                const int col0 = n0 + jb * 64 + tx * 4;
                float4 v;
                v.x = acc[i][jb * 4 + 0];
                v.y = acc[i][jb * 4 + 1];
                v.z = acc[i][jb * 4 + 2];
                v.w = acc[i][jb * 4 + 3];
                if (EPI == 1) {
                    v.x = tanhf(v.x + bias[col0 + 0]);
                    v.y = tanhf(v.y + bias[col0 + 1]);
                    v.z = tanhf(v.z + bias[col0 + 2]);
                    v.w = tanhf(v.w + bias[col0 + 3]);
                } else if (EPI == 2) {
                    v.x = 1.f / (1.f + __expf(-v.x));
                    v.y = 1.f / (1.f + __expf(-v.y));
                    v.z = 1.f / (1.f + __expf(-v.z));
                    v.w = 1.f / (1.f + __expf(-v.w));
                }
                *(float4*)(crow + col0) = v;
            }
        }
    }
}

__global__ __launch_bounds__(256)
void softmax_mul_f32(float* buf, const float* __restrict__ U, int Ncols)
{
    __shared__ float srow[8192];
    __shared__ float sred[8];
    const int t = threadIdx.x;
    const size_t base = (size_t)blockIdx.x * Ncols;

    float lmax = -3.402823466e38f;
    for (int c = t * 4; c < Ncols; c += 1024) {
        float4 v = *(const float4*)(buf + base + c);
        *(float4*)&srow[c] = v;
        lmax = fmaxf(lmax, fmaxf(fmaxf(v.x, v.y), fmaxf(v.z, v.w)));
    }
    const float rmax = blockReduceMax(lmax, sred);

    float lsum = 0.f;
    for (int c = t * 4; c < Ncols; c += 1024) {
        float4 v = *(float4*)&srow[c];
        v.x = __expf(v.x - rmax);
        v.y = __expf(v.y - rmax);
        v.z = __expf(v.z - rmax);
        v.w = __expf(v.w - rmax);
        *(float4*)&srow[c] = v;
        lsum += v.x + v.y + v.z + v.w;
    }
    const float rsum = blockReduceSum(lsum, sred);
    const float inv = 1.f / rsum;

    for (int c = t * 4; c < Ncols; c += 1024) {
        float4 e = *(float4*)&srow[c];
        float4 u = *(const float4*)(U + base + c);
        float4 o;
        o.x = u.x * e.x * inv;
        o.y = u.y * e.y * inv;
        o.z = u.z * e.z * inv;
        o.w = u.w * e.w * inv;
        *(float4*)(buf + base + c) = o;
    }
}

__global__ __launch_bounds__(256)
void softmax_inplace_small(float* buf, int D)
{
    __shared__ float sred[8];
    const int t = threadIdx.x;
    const size_t base = (size_t)blockIdx.x * D;
    float2 v = *(float2*)(buf + base + t * 2);
    const float rmax = blockReduceMax(fmaxf(v.x, v.y), sred);
    const float e0 = __expf(v.x - rmax);
    const float e1 = __expf(v.y - rmax);
    const float rsum = blockReduceSum(e0 + e1, sred);
    const float inv = 1.f / rsum;
    float2 o;
    o.x = e0 * inv;
    o.y = e1 * inv;
    *(float2*)(buf + base + t * 2) = o;
}

// ---------------------------------------------------------------- launch
extern "C" void kernel_launch(void* const* d_in, const int* in_sizes, int n_in,
                              void* d_out, int out_size, void* d_ws, size_t ws_size,
                              hipStream_t stream)
{
    const float* U  = (const float*)d_in[0];
    const float* X  = (const float*)d_in[1];
    const float* H1 = (const float*)d_in[2];
    const float* W0 = (const float*)d_in[3];
    const float* W1 = (const float*)d_in[4];
    const float* Wa = (const float*)d_in[5];
    const float* ba = (const float*)d_in[6];
    const int D = in_sizes[6];
    const int N = (int)((long long)in_sizes[2] / D);
    const size_t NN = (size_t)N * N, ND = (size_t)N * D;

    float* Xp = (float*)d_out;          // [N,N] final; scratch for L (as fp16)
    float* Zp = Xp + NN;                // [N,D] final Z

    char* p = (char*)d_ws;
    auto alloc = [&](size_t bytes) { char* r = p; p += (bytes + 255) & ~(size_t)255; return r; };
    unsigned short* wa_h  = (unsigned short*)alloc(ND * 2);
    unsigned short* h1_h  = (unsigned short*)alloc(ND * 2);
    unsigned short* k_h   = (unsigned short*)alloc(ND * 2);
    unsigned short* w0t_h = (unsigned short*)alloc(ND * 2);
    unsigned short* vbt   = (unsigned short*)alloc(ND * 2);
    unsigned short* zt_h  = (unsigned short*)alloc(ND * 2);
    unsigned short* uz_h  = (unsigned short*)alloc(ND * 2);
    unsigned short* w1t_h = (unsigned short*)alloc(ND * 2);
    float*          xw0f  = (float*)alloc(ND * 4);
    float*          cvec  = (float*)alloc((size_t)D * 4);
    float*          rsum  = (float*)alloc((size_t)N * 4);
    float*          Pp    = (float*)alloc(ND * 4 * 4);        // splitK=4 partials
    unsigned short* Php   = (unsigned short*)Pp;              // fp16 alias
    unsigned short* Uh    = (unsigned short*)alloc(NN * 2);
    unsigned short* Xh    = (unsigned short*)alloc(NN * 2);
    const size_t need = (size_t)(p - (char*)d_ws);

    dim3 blk(256), blk512(512);

    if (N == 8192 && D == 512 && ws_size >= need) {
        constexpr int LDS8P = 131072;
        bool ok8p = true;
        ok8p &= hipFuncSetAttribute((const void*)gemm8p<0>,
                    hipFuncAttributeMaxDynamicSharedMemorySize, LDS8P) == hipSuccess;
        ok8p &= hipFuncSetAttribute((const void*)gemm8p<2>,
                    hipFuncAttributeMaxDynamicSharedMemorySize, LDS8P) == hipSuccess;
        ok8p &= hipFuncSetAttribute((const void*)gemm8p<3>,
                    hipFuncAttributeMaxDynamicSharedMemorySize, LDS8P) == hipSuccess;

        unsigned short* Lh = (unsigned short*)Xp;
        const dim3 gSlim8(D / 256, N / 256, 4);    // (2,32,4) splitK slims
        const dim3 gBig8(N / 256, N / 256);        // (32,32) bigs
        const dim3 gSlimK(D / 128, N / 128, 4);
        const dim3 gBig(N / 256, N / 128);
        const dim3 gT(D / 32, N / 32);
        const dim3 gTw1(N / 32, D / 32);
        const dim3 gRed((unsigned)(ND / 1024));    // elementwise reduces
        const int cgrid = 4096;
        const float invN = 1.0f / (float)N;
        unsigned short* nullw = nullptr;
        const float* nullf = nullptr;

        auto slimGemmF = [&](const unsigned short* A_, const unsigned short* B_, float* C_) {
            if (ok8p)
                hipLaunchKernelGGL((gemm8p<0>), gSlim8, blk512, LDS8P, stream,
                                   A_, B_, C_, nullw, N, D, N);
            else
                hipLaunchKernelGGL((gemm_mfma<4, 2, 2, 0>), gSlimK, blk, 0, stream,
                                   A_, B_, C_, nullw, N, D, N);
        };

        // U -> fp16; Wa + H1 -> fp16 (merged launch)
        hipLaunchKernelGGL(convert_f16, dim3(cgrid), blk, 0, stream, U, Uh, NN);
        hipLaunchKernelGGL(convert2_f16, dim3((unsigned)(2 * ND / 1024)), blk, 0, stream,
                           Wa, wa_h, H1, h1_h, ND);
        // K = U @ Wa^T (splitK, fp16 partials) -> reduce w/ tanh+bias -> k fp16
        if (ok8p) {
            hipLaunchKernelGGL((gemm8p<3>), gSlim8, blk512, LDS8P, stream,
                               Uh, wa_h, (float*)nullptr, Php, N, D, N);
            hipLaunchKernelGGL((reduce_splitk_h<0>), gRed, blk, 0, stream,
                               Php, ND, ba, D, k_h);
        } else {
            hipLaunchKernelGGL((gemm_mfma<4, 2, 2, 0>), gSlimK, blk, 0, stream,
                               Uh, wa_h, Pp, nullw, N, D, N);
            hipLaunchKernelGGL((reduce_splitk<0>), gRed, blk, 0, stream,
                               Pp, ND, ba, D, (float*)nullptr, k_h);
        }
        // L = K @ H1^T -> fp16 Lh
        if (ok8p)
            hipLaunchKernelGGL((gemm8p<3>), gBig8, blk512, LDS8P, stream,
                               k_h, h1_h, (float*)nullptr, Lh, N, N, D);
        else
            hipLaunchKernelGGL((gemm_mfma<4, 2, 4, 3>), gBig, blk512, 0, stream,
                               k_h, h1_h, (float*)nullptr, Lh, N, N, D);
        // X -> fp16
        hipLaunchKernelGGL(convert_f16, dim3(cgrid), blk, 0, stream, X, Xh, NN);
        hipLaunchKernelGGL((transpose_cvt<false>), gT, blk, 0, stream, W0, w0t_h, nullf, 0.f, N, D);
        // XW0 = X @ W0 (splitK, f32 partials) -> reduce -> xw0f
        slimGemmF(Xh, w0t_h, Pp);
        hipLaunchKernelGGL((reduce_splitk<1>), gRed, blk, 0, stream,
                           Pp, ND, nullf, D, xw0f, nullw);
        // raw column sums of XW0
        hipMemsetAsync(cvec, 0, (size_t)D * 4, stream);
        hipLaunchKernelGGL(colsum512, dim3(N / 16), blk, 0, stream, xw0f, cvec, N);
        // V = (XW0 - cvec*invN)^T -> fp16 [D][N]
        hipLaunchKernelGGL((transpose_cvt<true>), gT, blk, 0, stream, xw0f, vbt, cvec, invN, N, D);
        // A2s = 1024 * Uh * softmax(L fp16) -> fp16 + rowsum
        hipLaunchKernelGGL(softmax_mul_f16s, dim3(N), blk, 0, stream, Lh, Uh, Xh, rsum, N);
        // T = A2s @ V (splitK, f32 partials); fused reduce+affine+softmax+transpose
        slimGemmF(Xh, vbt, Pp);
        hipLaunchKernelGGL(reduce_softmax4_t, dim3(N / 4), blk, 0, stream,
                           Pp, ND, rsum, cvec, 1.0f / 1024.f, invN, Zp, zt_h, N);
        // UZ = U @ Z (splitK, fp16 partials) -> reduce -> uz fp16
        if (ok8p) {
            hipLaunchKernelGGL((gemm8p<3>), gSlim8, blk512, LDS8P, stream,
                               Uh, zt_h, (float*)nullptr, Php, N, D, N);
            hipLaunchKernelGGL((reduce_splitk_h<3>), gRed, blk, 0, stream,
                               Php, ND, nullf, D, uz_h);
        } else {
            hipLaunchKernelGGL((gemm_mfma<4, 2, 2, 0>), gSlimK, blk, 0, stream,
                               Uh, zt_h, Pp, nullw, N, D, N);
            hipLaunchKernelGGL((reduce_splitk<3>), gRed, blk, 0, stream,
                               Pp, ND, nullf, D, (float*)nullptr, uz_h);
        }
        hipLaunchKernelGGL((transpose_cvt<false>), gTw1, blk, 0, stream, W1, w1t_h, nullf, 0.f, D, N);
        // Xp = sigmoid(UZ @ W1)
        if (ok8p)
            hipLaunchKernelGGL((gemm8p<2>), gBig8, blk512, LDS8P, stream,
                               uz_h, w1t_h, Xp, nullw, N, N, D);
        else
            hipLaunchKernelGGL((gemm_mfma<4, 2, 4, 2>), gBig, blk512, 0, stream,
                               uz_h, w1t_h, Xp, nullw, N, N, D);
    } else {
        // -------- fp32 fallback
        float* bufA = (float*)d_ws;
        dim3 gD(D / 128, N / 128);
        dim3 gN(N / 128, N / 128);
        hipLaunchKernelGGL((gemm_f32<1, true>),  gD, blk, 0, stream, U,    Wa, ba,      bufA, N, D, N);
        hipLaunchKernelGGL((gemm_f32<0, true>),  gN, blk, 0, stream, bufA, H1, nullptr, Xp,   N, N, D);
        hipLaunchKernelGGL(softmax_mul_f32, dim3(N), blk, 0, stream, Xp, U, N);
        hipLaunchKernelGGL((gemm_f32<0, false>), gD, blk, 0, stream, X,    W0, nullptr, bufA, N, D, N);
        hipLaunchKernelGGL((gemm_f32<0, false>), gD, blk, 0, stream, Xp,   bufA, nullptr, Zp, N, D, N);
        hipLaunchKernelGGL(softmax_inplace_small, dim3(N), blk, 0, stream, Zp, D);
        hipLaunchKernelGGL((gemm_f32<0, false>), gD, blk, 0, stream, U,    Zp, nullptr, bufA, N, D, N);
        hipLaunchKernelGGL((gemm_f32<2, false>), gN, blk, 0, stream, bufA, W1, nullptr, Xp,  N, N, D);
    }
}